// Round 12
// baseline (444.648 us; speedup 1.0000x reference)
//
#include <hip/hip_runtime.h>
#include <math.h>

// TNO block, round 12: round-11 + two producer/consumer fusions:
//  - k_spec = p1+p2+build_k (one block per map; x-map, R, Xt, K'' all LDS-resident)
//  - k_zcorr = zp+corr (thread owns one corner mode for all 8 heads; Zc never hits HBM)
// Spectra: forward-normalized, x[y][n] = sum A e^{+2pi i(ky y+kx n)/128}.

#define NT 2112   // 64*33 truncated spectrum per map

__device__ __forceinline__ void blockReduce2(float& a, float& b, float* red){
  const int tid = threadIdx.x, n = blockDim.x;
  red[tid] = a; red[n+tid] = b;
  __syncthreads();
  for(int off=n>>1; off>0; off>>=1){
    if(tid<off){ red[tid]+=red[tid+off]; red[n+tid]+=red[n+tid+off]; }
    __syncthreads();
  }
  a = red[0]; b = red[n];
  __syncthreads();
}

__device__ __forceinline__ float2 cmul_add(float2 acc, float2 w, float2 x){
  acc.x += w.x*x.x - w.y*x.y;
  acc.y += w.x*x.y + w.y*x.x;
  return acc;
}

// ---------------- twiddle table: CS[a*128+b] = (cos,sin)(2pi a b/128) ----------
__global__ void k_tables(float2* __restrict__ CS){
  int a = blockIdx.x, b = threadIdx.x;
  int p = (a*b)&127;
  float t = (float)p * (1.0f/64.0f);
  CS[a*128+b] = make_float2(cospif(t), sinpif(t));
}

// ---------------- per-map IN stats of x: alpha1 = w*rs, beta1 = b - mu*alpha ---
__global__ __launch_bounds__(256) void k_instats(
    const float* __restrict__ xin, const float* __restrict__ n1w,
    const float* __restrict__ n1b, float* __restrict__ a1, float* __restrict__ b1)
{
  __shared__ float red[512];
  const int m = blockIdx.x, t = threadIdx.x;
  const float* xp = xin + (size_t)m*16384;
  float s1=0.f, s2=0.f;
  for(int i=t;i<4096;i+=256){
    float4 v = ((const float4*)xp)[i];
    s1 += v.x+v.y+v.z+v.w;
    s2 += v.x*v.x+v.y*v.y+v.z*v.z+v.w*v.w;
  }
  blockReduce2(s1,s2,red);
  if(t==0){
    float mu = s1*(1.0f/16384.0f);
    float var = s2*(1.0f/16384.0f)-mu*mu;
    float a = n1w[0]*rsqrtf(var+1e-5f);
    a1[m] = a; b1[m] = n1b[0] - mu*a;
  }
}

// ---------------- k_spec: x -> Xt2 (+Xp gather) -> Kc, one block per map -------
__global__ __launch_bounds__(512) void k_spec(
    const float* __restrict__ xin, const float2* __restrict__ CS,
    const float* __restrict__ a1, const float* __restrict__ n1b,
    const float* __restrict__ kqv_wr, const float* __restrict__ kqv_wi,
    const float* __restrict__ kqv_bias, const float* __restrict__ kqv_sw,
    const float* __restrict__ kqv_sb,
    float2* __restrict__ Xt2, float2* __restrict__ Xp, float2* __restrict__ Kc)
{
  __shared__ float xl[128*129];        // 66 KB
  __shared__ float2 Rst[128*33];       // 34 KB
  __shared__ float2 Xt2l[2112];        // 17 KB
  __shared__ float2 Ksl[2112];         // 17 KB
  const int m = blockIdx.x, t = threadIdx.x;
  // load map (coalesced float4)
  {
    const float4* xp4 = (const float4*)(xin + (size_t)m*16384);
    for(int i4=t;i4<4096;i4+=512){
      float4 v = xp4[i4];
      int y = i4>>5, n = (i4&31)*4;
      xl[y*129+n]=v.x; xl[y*129+n+1]=v.y; xl[y*129+n+2]=v.z; xl[y*129+n+3]=v.w;
    }
  }
  __syncthreads();
  // stage 1: R[y][c] = sum_n x[y][n] e^{-2pi i c n/128}
  {
    const int yl = t&31, cgrp = t>>5;        // cgrp in [0,16)
    const int nc = (cgrp==0)?3:2;            // c = cgrp, cgrp+16, (32 if cgrp==0)
    for(int yt=0; yt<4; yt++){
      int y = yt*32 + yl;
      float ar[3]={0,0,0}, ai[3]={0,0,0};
      for(int n=0;n<128;n++){
        float xv = xl[y*129+n];
        #pragma unroll
        for(int k=0;k<3;k++){
          if(k<nc){
            float2 cs = CS[(cgrp+16*k)*128+n];
            ar[k] += xv*cs.x;
            ai[k] -= xv*cs.y;
          }
        }
      }
      #pragma unroll
      for(int k=0;k<3;k++){
        if(k<nc){
          int c = cgrp+16*k;
          Rst[y*33+c] = make_float2(ar[k], ai[k]);
        }
      }
    }
  }
  __syncthreads();
  // stage 2: Xt[r*33+c] = sum_y R[y][c] e^{-2pi i ky y/128}, ky=(r<32)?r:r+64
  {
    const float sc = a1[m]*(1.0f/16384.0f);
    const int r = t&63, cg = t>>6;           // cg in [0,8)
    const int ky = (r<32)? r : r+64;
    const int nk = (cg==0)?5:4;
    #pragma unroll
    for(int k=0;k<5;k++){
      if(k<nk){
        int c = cg + 8*k;
        float ar=0.f, ai=0.f;
        for(int y=0;y<128;y++){
          float2 Rv = Rst[y*33+c];           // wave-uniform broadcast
          float2 cs = CS[128 + ((ky*y)&127)];
          ar += Rv.x*cs.x + Rv.y*cs.y;
          ai += Rv.y*cs.x - Rv.x*cs.y;
        }
        int j = r*33 + c;
        float vr = ar*sc, vi = ai*sc;
        if(j==0){ vr = n1b[0]; vi = 0.f; }
        float2 val = make_float2(vr, vi);
        Xt2[m*NT+j] = val;
        Xt2l[j] = val;
        if(c<16 && (r<16 || r>=48)){
          int rp = (r<16)? r : r-32;
          Xp[m*512 + rp*16 + c] = val;
        }
      }
    }
  }
  __syncthreads();
  // build K'' = wsc * conj(A) * Pi(B*X) per head, DC zeroed
  for(int o=0;o<8;o++){
    const float swK = kqv_sw[o];
    const float swQ = kqv_sw[8+o];
    for(int j=t;j<2112;j+=512){
      int r = j/33, c = j - r*33;
      float2 X = Xt2l[j];
      float2 K = make_float2(swK*X.x, swK*X.y);
      if(c<8){
        int wrow = (r<8)? r : ((r>=56)? r-48 : -1);
        if(wrow>=0)
          K = cmul_add(K, make_float2(kqv_wr[(o*16+wrow)*8+c], kqv_wi[(o*16+wrow)*8+c]), X);
      }
      if(j==0) K.x += kqv_bias[o] + kqv_sb[o];
      Ksl[j] = K;
    }
    __syncthreads();
    const size_t ob = ((size_t)(m*8+o))*NT;
    for(int j=t;j<2112;j+=512){
      int r = j/33, c = j - r*33;
      float2 K = Ksl[j];
      float wsc = 128.0f;
      if(c==0 || c==32){
        int pj = ((64-r)&63)*33 + c;
        float2 K2 = Ksl[pj];
        K = make_float2(0.5f*(K.x+K2.x), 0.5f*(K.y-K2.y));
        wsc = 64.0f;
      }
      float ar = swQ, ai = 0.f;
      if(c<8){
        int wrow = (r<8)? r : ((r>=56)? r-48 : -1);
        if(wrow>=0){ ar += kqv_wr[((8+o)*16+wrow)*8+c]; ai += kqv_wi[((8+o)*16+wrow)*8+c]; }
      }
      float2 out = make_float2(wsc*(ar*K.x + ai*K.y), wsc*(ar*K.y - ai*K.x));
      if(j==0) out = make_float2(0.f, 0.f);
      Kc[ob+j] = out;
    }
    __syncthreads();
  }
}

// ---------------- scores SGEMM: Q-side = raw Xt2; 64x64 tiles, 4x4 accs --------
__global__ __launch_bounds__(256) void k_scores(
  const float2* __restrict__ Xt2, const float2* __restrict__ Kc,
  float* __restrict__ Pp)
{
  __shared__ float Qs[64*52];
  __shared__ float Ks[64*52];
  const int bid = blockIdx.x;
  const int fq = bid&15, st = (bid>>4)&1, tt = (bid>>5)&1, h = (bid>>6)&7, b = bid>>9;
  const int t = threadIdx.x;
  const int tg = t>>4, sg = t&15;
  const int t0 = tt*64, s0 = st*64;
  const int f2base = fq*132;
  float acc[4][4];
  #pragma unroll
  for(int i=0;i<4;i++)
    #pragma unroll
    for(int j=0;j<4;j++) acc[i][j]=0.f;
  for(int sub=0; sub<6; sub++){
    __syncthreads();
    const int fo = f2base + sub*22;
    for(int idx=t; idx<1408; idx+=256){
      int rl = idx/22, f2 = idx - rl*22;
      float2 q = Xt2[(size_t)(b*128 + t0+rl)*NT + fo + f2];
      ((float2*)(Qs + rl*52))[f2] = q;
      float2 kk = Kc[((size_t)((b*128 + s0+rl)*8+h))*NT + fo + f2];
      ((float2*)(Ks + rl*52))[f2] = kk;
    }
    __syncthreads();
    #pragma unroll
    for(int f4=0; f4<11; f4++){
      float4 qv[4], kv[4];
      #pragma unroll
      for(int i=0;i<4;i++) qv[i] = *(const float4*)&Qs[(tg+16*i)*52 + f4*4];
      #pragma unroll
      for(int j=0;j<4;j++) kv[j] = *(const float4*)&Ks[(sg+16*j)*52 + f4*4];
      #pragma unroll
      for(int i=0;i<4;i++)
        #pragma unroll
        for(int j=0;j<4;j++)
          acc[i][j] += qv[i].x*kv[j].x + qv[i].y*kv[j].y
                     + qv[i].z*kv[j].z + qv[i].w*kv[j].w;
    }
  }
  #pragma unroll
  for(int i=0;i<4;i++){
    int tg2 = t0 + tg + 16*i;
    #pragma unroll
    for(int j=0;j<4;j++){
      int s = s0 + sg + 16*j;
      Pp[(size_t)fq*262144 + ((size_t)((b*8+h)*128+tg2))*128 + s] = acc[i][j];
    }
  }
}

__global__ __launch_bounds__(64) void k_softmax(const float* __restrict__ Pp,
                                                float* __restrict__ P){
  const int row = blockIdx.x, tid = threadIdx.x;
  size_t o = (size_t)row*128;
  float v0=0.f, v1=0.f;
  #pragma unroll
  for(int q=0;q<16;q++){
    v0 += Pp[(size_t)q*262144 + o + tid];
    v1 += Pp[(size_t)q*262144 + o + tid + 64];
  }
  float mx = fmaxf(v0,v1);
  for(int off=32; off; off>>=1) mx = fmaxf(mx, __shfl_xor(mx, off));
  float e0 = expf(v0-mx), e1 = expf(v1-mx);
  float s = e0+e1;
  for(int off=32; off; off>>=1) s += __shfl_xor(s, off);
  float inv = 1.0f/s;
  P[o+tid] = e0*inv; P[o+tid+64] = e1*inv;
}

// PA^T[b][s][t] = alpha1[b*128+s] * sum_h psw*sv*P[b,h,t,s]
__global__ __launch_bounds__(256) void k_peff(const float* __restrict__ P,
   const float* __restrict__ p_sw, const float* __restrict__ kqv_sw,
   const float* __restrict__ a1, float* __restrict__ PAT)
{
  const int i = blockIdx.x*256 + threadIdx.x;
  const int b = i>>14, rem = i&16383;
  const int tch = rem>>7, s = rem&127;
  float acc=0.f;
  for(int hh=0; hh<8; hh++){
    float a = p_sw[hh]*kqv_sw[16+hh];
    acc += a * P[(((size_t)(b*8+hh))<<14) + rem];
  }
  PAT[((size_t)(b*128+s))*128 + tch] = acc * a1[b*128+s];
}

// pbeta[b*128+t] = sum_s (sum_h psw*sv*P) * beta1[b*128+s]
__global__ __launch_bounds__(128) void k_pbeta(const float* __restrict__ P,
   const float* __restrict__ p_sw, const float* __restrict__ kqv_sw,
   const float* __restrict__ b1, float* __restrict__ pbeta)
{
  __shared__ float red[128];
  const int bid = blockIdx.x;
  const int b = bid>>7, tch = bid&127;
  const int s = threadIdx.x;
  float acc=0.f;
  for(int hh=0; hh<8; hh++){
    float a = p_sw[hh]*kqv_sw[16+hh];
    acc += a * P[((size_t)((b*8+hh)*128+tch))*128 + s];
  }
  acc *= b1[b*128+s];
  red[s] = acc; __syncthreads();
  for(int off=64; off>0; off>>=1){
    if(s<off) red[s]+=red[s+off];
    __syncthreads();
  }
  if(s==0) pbeta[bid] = red[0];
}

// ---------------- k_zcorr: Z (per map, all heads, all 512 modes) + corr --------
// block m = b*128+cix, 512 threads; thread owns mode j=t for all 8 heads.
__global__ __launch_bounds__(512) void k_zcorr(
  const float* __restrict__ P, const float2* __restrict__ Xp,
  const float* __restrict__ kqv_wr, const float* __restrict__ kqv_wi,
  const float* __restrict__ kqv_bias, const float* __restrict__ kqv_sw, const float* __restrict__ kqv_sb,
  const float* __restrict__ p_wr, const float* __restrict__ p_wi,
  const float* __restrict__ p_bias, const float* __restrict__ p_sw, const float* __restrict__ p_sb,
  float2* __restrict__ Bc)
{
  __shared__ float4 Xs4[4096];        // 64 KB: staged Xp s-tiles; later Zl
  __shared__ float Pl[1024];
  const int m = blockIdx.x;
  const int b = m>>7, cix = m&127;
  const int t = threadIdx.x;
  const int j = t;                     // mode index
  for(int idx=t; idx<1024; idx+=512){
    int o = idx>>7, s = idx&127;
    Pl[idx] = P[((size_t)((b*8+o)*128 + cix))*128 + s];
  }
  float2 z[8];
  #pragma unroll
  for(int o=0;o<8;o++) z[o] = make_float2(0.f,0.f);
  const float2* Xs = (const float2*)Xs4;
  for(int st=0; st<8; st++){
    __syncthreads();
    for(int q=t; q<4096; q+=512){
      int sl = q>>8, f4 = q&255;
      Xs4[q] = ((const float4*)(Xp + (size_t)(b*128 + st*16 + sl)*512))[f4];
    }
    __syncthreads();
    for(int sl=0; sl<16; sl++){
      int s = st*16 + sl;
      float2 xv = Xs[sl*512 + j];
      #pragma unroll
      for(int o=0;o<8;o++){
        float p = Pl[o*128+s];
        z[o].x += p*xv.x; z[o].y += p*xv.y;
      }
    }
  }
  __syncthreads();
  float2* Zl = (float2*)Xs4;           // 8 x 512 complex = 32 KB (Xs dead)
  #pragma unroll
  for(int o=0;o<8;o++) Zl[o*512 + j] = z[o];
  __syncthreads();
  // corr epilogue (identical math to k_corr, Zl-local)
  {
    int r = j>>4, c = j&15;
    int ky = (r<16)? r : 96+r;
    float accr=0.f, acci=0.f;
    int rp = -1;
    if(c==0){ int kyp = (128-ky)&127; rp = (kyp<16)? kyp : ((kyp>=112)? kyp-96 : -1); }
    for(int o=0;o<8;o++){
      float2 zv = Zl[o*512 + j];
      float cvr=0.f, cvi=0.f;
      bool inV = (c<8) && (ky<8 || ky>=120);
      if(inV){
        int vrow = (ky<8)? ky : 8+(ky-120);
        float wr = kqv_wr[((16+o)*16+vrow)*8+c], wi = kqv_wi[((16+o)*16+vrow)*8+c];
        cvr = wr*zv.x - wi*zv.y; cvi = wr*zv.y + wi*zv.x;
      }
      float ar = cvr, ai = cvi;
      if(c==0){
        float pvr=0.f, pvi=0.f;
        int kyp = (128-ky)&127;
        bool pInV = (kyp<8 || kyp>=120);
        if(pInV && rp>=0){
          int vrow = (kyp<8)? kyp : 8+(kyp-120);
          float2 z2 = Zl[o*512 + rp*16];
          float wr = kqv_wr[((16+o)*16+vrow)*8], wi = kqv_wi[((16+o)*16+vrow)*8];
          pvr = wr*z2.x - wi*z2.y; pvi = wr*z2.y + wi*z2.x;
        }
        ar = 0.5f*(cvr + pvr);
        ai = 0.5f*(cvi - pvi);
      }
      float sv = kqv_sw[16+o];
      float Dv = kqv_bias[16+o] + kqv_sb[16+o];
      float atr = sv*zv.x + ar + ((j==0)? Dv : 0.f);
      float ati = sv*zv.y + ai;
      float psw = p_sw[o];
      accr += psw*ar;  acci += psw*ai;
      float wpr = p_wr[(o*32+r)*16+c], wpi = p_wi[(o*32+r)*16+c];
      accr += wpr*atr - wpi*ati;
      acci += wpr*ati + wpi*atr;
      if(j==0) accr += psw*Dv;
    }
    if(j==0) accr += p_bias[0] + p_sb[0];
    Bc[m*512+j] = make_float2(accr, acci);
  }
}

// ---------------- attn GEMM: y0g[b,c][p] = sum_s PA^T[s][c] * x[s][p] + pbeta --
__global__ __launch_bounds__(256) void k_attn_gemm(
  const float* __restrict__ PAT, const float* __restrict__ xin,
  const float* __restrict__ pbeta, float* __restrict__ y0g)
{
  __shared__ float PAs[32*33];
  __shared__ float Xs[32*256];
  const int bid = blockIdx.x;
  const int b = bid>>8, ct = (bid>>6)&3, pt = bid&63;
  const int t = threadIdx.x;
  const int tc = t>>6, tp = t&63;
  float4 acc[8];
  #pragma unroll
  for(int k=0;k<8;k++) acc[k] = make_float4(0.f,0.f,0.f,0.f);
  for(int sc4=0; sc4<4; sc4++){
    __syncthreads();
    for(int idx=t; idx<1024; idx+=256){
      int sl = idx>>5, cl = idx&31;
      PAs[sl*33+cl] = PAT[((size_t)(b*128 + sc4*32+sl))*128 + ct*32+cl];
    }
    for(int q=t; q<2048; q+=256){
      int sl = q>>6, p4 = q&63;
      ((float4*)Xs)[q] =
        ((const float4*)xin)[((size_t)(b*128 + sc4*32+sl))*4096 + pt*64 + p4];
    }
    __syncthreads();
    for(int sl=0; sl<32; sl++){
      float4 xv = ((const float4*)Xs)[sl*64+tp];
      #pragma unroll
      for(int k=0;k<8;k++){
        float pa = PAs[sl*33 + tc*8+k];
        acc[k].x += pa*xv.x; acc[k].y += pa*xv.y;
        acc[k].z += pa*xv.z; acc[k].w += pa*xv.w;
      }
    }
  }
  #pragma unroll
  for(int k=0;k<8;k++){
    int c = ct*32 + tc*8 + k;
    float pb = pbeta[b*128+c];
    float4 o = acc[k];
    o.x += pb; o.y += pb; o.z += pb; o.w += pb;
    ((float4*)y0g)[((size_t)(b*128+c))*4096 + pt*64 + tp] = o;
  }
}

// ---------------- epi0 (512 threads): attn = IN(y0g+cinv(Bc)+x)*aw+ab ; + Hc ---
__global__ __launch_bounds__(512) void k_epi0(
  const float* __restrict__ y0g, const float* __restrict__ xin,
  const float2* __restrict__ Bc,
  const float2* __restrict__ CS,
  const float* __restrict__ awp, const float* __restrict__ abp,
  const float* __restrict__ n2w, const float* __restrict__ n2b,
  float* __restrict__ attn, float* __restrict__ a2, float* __restrict__ b2,
  float2* __restrict__ Hc)
{
  __shared__ float2 Bcl[512];
  __shared__ float2 V[128*17];        // reused as Rc in the corner DFT
  __shared__ float V2p[128*132];
  __shared__ float red[1024];
  const int m = blockIdx.x, t = threadIdx.x;
  Bcl[t] = Bc[m*512+t];
  __syncthreads();
  #pragma unroll
  for(int k=0;k<4;k++){
    int idx = t + 512*k;
    int mm = idx>>4, c = idx&15;
    float vr=0.f, vi=0.f;
    for(int r=0;r<32;r++){
      int ky = (r<16)? r : 96+r;
      float2 bc = Bcl[r*16+c];
      float2 cs = CS[128 + ((ky*mm)&127)];
      vr += bc.x*cs.x - bc.y*cs.y;
      vi += bc.x*cs.y + bc.y*cs.x;
    }
    float w = (c==0)?1.0f:2.0f;
    V[mm*17+c] = make_float2(vr*w, vi*w);
  }
  __syncthreads();
  {
    const int n = t&127, mm0 = t>>7;
    float2 csr[16];
    #pragma unroll
    for(int c=0;c<16;c++) csr[c] = CS[c*128+n];
    for(int k=0;k<32;k++){
      int mm = mm0 + 4*k;
      float cv = 0.f;
      #pragma unroll
      for(int c=0;c<16;c++){
        float2 v2 = V[mm*17+c];
        cv += v2.x*csr[c].x - v2.y*csr[c].y;
      }
      V2p[mm*132+n] = cv;
    }
  }
  __syncthreads();
  const float4* x4 = (const float4*)(xin + (size_t)m*16384);
  const float4* g4 = (const float4*)(y0g + (size_t)m*16384);
  float4* V24 = (float4*)V2p;
  float s1=0.f, s2=0.f;
  for(int k=0;k<8;k++){
    int q = t + 512*k;
    int row = q>>5, c4 = q&31;
    float4 xv = x4[q], gv = g4[q], cc = V24[row*33+c4];
    float4 v;
    v.x = xv.x+gv.x+cc.x; v.y = xv.y+gv.y+cc.y;
    v.z = xv.z+gv.z+cc.z; v.w = xv.w+gv.w+cc.w;
    s1 += v.x+v.y+v.z+v.w;
    s2 += v.x*v.x+v.y*v.y+v.z*v.z+v.w*v.w;
    V24[row*33+c4] = v;
  }
  blockReduce2(s1,s2,red);
  float mu = s1*(1.0f/16384.0f);
  float var = s2*(1.0f/16384.0f)-mu*mu;
  float rs = rsqrtf(var+1e-5f);
  float aw = awp[0], ab = abp[0];
  float4* at4 = (float4*)(attn + (size_t)m*16384);
  for(int k=0;k<8;k++){
    int q = t + 512*k;
    int row = q>>5, c4 = q&31;
    float4 v = V24[row*33+c4];
    float4 ov;
    ov.x = (v.x-mu)*rs*aw + ab;
    ov.y = (v.y-mu)*rs*aw + ab;
    ov.z = (v.z-mu)*rs*aw + ab;
    ov.w = (v.w-mu)*rs*aw + ab;
    at4[q] = ov;
  }
  float va = aw*aw*var/(var+1e-5f);
  float al = n2w[m&3]*rsqrtf(va+1e-5f);
  if(t==0){ a2[m] = al; b2[m] = n2b[m&3] - ab*al; }
  __syncthreads();
  {  // corner DFT stage 1
    const int yl = t&31, c = t>>5;
    for(int yc=0; yc<4; yc++){
      int y = yc*32+yl;
      float ar=0.f, ai=0.f;
      for(int n=0;n<128;n++){
        float zv = V2p[y*132+n];
        float2 cs = CS[c*128+n];
        ar += zv*cs.x; ai -= zv*cs.y;
      }
      V[y*17+c] = make_float2(ar, ai);
    }
  }
  __syncthreads();
  {  // stage 2
    const float scl = al*rs*aw*(1.0f/16384.0f);
    int idx = t;
    int r = idx>>4, c = idx&15;
    int ky = (r<16)? r : 96+r;
    float hr=0.f, hi=0.f;
    for(int y=0;y<128;y++){
      float2 Rv = V[y*17+c];
      float2 cs = CS[128 + ((ky*y)&127)];
      hr += Rv.x*cs.x + Rv.y*cs.y;
      hi += Rv.y*cs.x - Rv.x*cs.y;
    }
    float2 o = make_float2(hr*scl, hi*scl);
    if(idx==0) o = make_float2(n2b[m&3], 0.f);
    Hc[m*512+idx] = o;
  }
}

// ---------------- mixer spectral: S = sum_i w.Hc ; IN in freq -> Sn ------------
__global__ __launch_bounds__(256) void k_mixc(
  const float2* __restrict__ Hc,
  const float* __restrict__ wr0, const float* __restrict__ wi0,
  float2* __restrict__ Sn)
{
  __shared__ float2 Sl[512];
  __shared__ float red[512];
  const int mb = blockIdx.x;
  const int g = mb&63, o = mb>>6;
  const int t = threadIdx.x;
  for(int j=t;j<512;j+=256){
    int r = j>>4, c = j&15;
    float ar=0.f, ai=0.f;
    for(int i2=0;i2<4;i2++){
      float2 h = Hc[(g*4+i2)*512 + j];
      float wr = wr0[((i2*4+o)*32+r)*16+c], wi = wi0[((i2*4+o)*32+r)*16+c];
      ar += wr*h.x - wi*h.y; ai += wr*h.y + wi*h.x;
    }
    Sl[j] = make_float2(ar, ai);
  }
  __syncthreads();
  float vs=0.f, dummy=0.f;
  for(int j=t;j<512;j+=256){
    int c=j&15;
    if(c>=1) vs += 2.0f*(Sl[j].x*Sl[j].x + Sl[j].y*Sl[j].y);
  }
  if(t<32){
    int ky = (t<16)? (t+1) : (96+t);
    float ar=0.f, ai=0.f;
    if(ky<16){ ar=Sl[ky*16].x; ai=Sl[ky*16].y; }
    else if(ky>=112){ int r=ky-96; ar=Sl[r*16].x; ai=Sl[r*16].y; }
    int kyp = 128-ky;
    float br2=0.f, bi2=0.f;
    if(kyp<16){ br2=Sl[kyp*16].x; bi2=Sl[kyp*16].y; }
    else if(kyp>=112){ int r=kyp-96; br2=Sl[r*16].x; bi2=Sl[r*16].y; }
    float pr = 0.5f*(ar+br2), pi = 0.5f*(ai-bi2);
    vs += pr*pr + pi*pi;
  }
  blockReduce2(vs, dummy, red);
  float rs2 = rsqrtf(vs + 1e-5f);
  for(int j=t;j<512;j+=256){
    float2 s = Sl[j];
    if(j==0) Sn[(g*4+o)*512+j] = make_float2(0.f,0.f);
    else     Sn[(g*4+o)*512+j] = make_float2(s.x*rs2, s.y*rs2);
  }
}

// ---------------- mixer inverse (512 threads; +opt Hc emit / final IN+add) -----
__global__ __launch_bounds__(512) void k_mixinv(
  const float2* __restrict__ Sn, const float* __restrict__ inmaps,
  const float* __restrict__ a2, const float* __restrict__ b2,
  const float* __restrict__ msw, const float* __restrict__ msb,
  const float2* __restrict__ CS, const int dogelu,
  float2* __restrict__ HcOut,
  const float* __restrict__ addsrc, const float* __restrict__ mw,
  const float* __restrict__ mbv,
  float* __restrict__ outp)
{
  __shared__ float2 Sl[512];
  __shared__ float2 V[128*17];        // reused as Rc
  __shared__ float V2p[128*132];
  __shared__ float red[1024];
  const int mb = blockIdx.x;
  const int g = mb&63, o = mb>>6;
  const int mmap = g*4+o;
  const int t = threadIdx.x;
  float cw[4]; float cb = msb[o];
  #pragma unroll
  for(int i=0;i<4;i++){
    float al = a2 ? a2[g*4+i] : 1.0f;
    float be = b2 ? b2[g*4+i] : 0.0f;
    float sw = msw[o*4+i];
    cw[i] = sw*al; cb += sw*be;
  }
  Sl[t] = Sn[mmap*512+t];
  __syncthreads();
  #pragma unroll
  for(int k=0;k<4;k++){
    int idx = t + 512*k;
    int mm = idx>>4, c = idx&15;
    float vr=0.f, vi=0.f;
    for(int r=0;r<32;r++){
      int ky = (r<16)? r : 96+r;
      float2 bc = Sl[r*16+c];
      float2 cs = CS[128 + ((ky*mm)&127)];
      vr += bc.x*cs.x - bc.y*cs.y;
      vi += bc.x*cs.y + bc.y*cs.x;
    }
    float w = (c==0)?1.0f:2.0f;
    V[mm*17+c] = make_float2(vr*w, vi*w);
  }
  __syncthreads();
  {
    const int n = t&127, mm0 = t>>7;
    float2 csr[16];
    #pragma unroll
    for(int c=0;c<16;c++) csr[c] = CS[c*128+n];
    for(int k=0;k<32;k++){
      int mm = mm0 + 4*k;
      float cv = 0.f;
      #pragma unroll
      for(int c=0;c<16;c++){
        float2 v2 = V[mm*17+c];
        cv += v2.x*csr[c].x - v2.y*csr[c].y;
      }
      V2p[mm*132+n] = cv;
    }
  }
  __syncthreads();
  const float4* in4 = (const float4*)(inmaps + (size_t)(g*4)*16384);
  float4* V24 = (float4*)V2p;
  float4* o4 = (float4*)(outp + (size_t)mmap*16384);
  float s1=0.f, s2=0.f;
  for(int k=0;k<8;k++){
    int q = t + 512*k;
    int row = q>>5, c4 = q&31;
    float4 v0 = in4[q], v1 = in4[4096+q], v2 = in4[8192+q], v3 = in4[12288+q];
    float4 cc = V24[row*33+c4];
    float4 ov;
    ov.x = cb + cw[0]*v0.x + cw[1]*v1.x + cw[2]*v2.x + cw[3]*v3.x + cc.x;
    ov.y = cb + cw[0]*v0.y + cw[1]*v1.y + cw[2]*v2.y + cw[3]*v3.y + cc.y;
    ov.z = cb + cw[0]*v0.z + cw[1]*v1.z + cw[2]*v2.z + cw[3]*v3.z + cc.z;
    ov.w = cb + cw[0]*v0.w + cw[1]*v1.w + cw[2]*v2.w + cw[3]*v3.w + cc.w;
    if(dogelu){
      ov.x = 0.5f*ov.x*(1.0f+erff(ov.x*0.70710678118f));
      ov.y = 0.5f*ov.y*(1.0f+erff(ov.y*0.70710678118f));
      ov.z = 0.5f*ov.z*(1.0f+erff(ov.z*0.70710678118f));
      ov.w = 0.5f*ov.w*(1.0f+erff(ov.w*0.70710678118f));
    }
    if(addsrc){
      s1 += ov.x+ov.y+ov.z+ov.w;
      s2 += ov.x*ov.x+ov.y*ov.y+ov.z*ov.z+ov.w*ov.w;
      V24[row*33+c4] = ov;
    } else {
      o4[q] = ov;
      if(HcOut) V24[row*33+c4] = ov;
    }
  }
  if(addsrc){
    blockReduce2(s1,s2,red);
    float mu = s1*(1.0f/16384.0f);
    float var = s2*(1.0f/16384.0f)-mu*mu;
    float rs = rsqrtf(var+1e-5f);
    float w = mw[o], b = mbv[o];
    const float4* a4 = (const float4*)(addsrc + (size_t)mmap*16384);
    for(int k=0;k<8;k++){
      int q = t + 512*k;
      int row = q>>5, c4 = q&31;
      float4 v = V24[row*33+c4], av = a4[q];
      float4 ov;
      ov.x = (v.x-mu)*rs*w + b + av.x;
      ov.y = (v.y-mu)*rs*w + b + av.y;
      ov.z = (v.z-mu)*rs*w + b + av.z;
      ov.w = (v.w-mu)*rs*w + b + av.w;
      o4[q] = ov;
    }
  }
  if(HcOut){
    __syncthreads();
    {  // stage 1 (V reused as Rc)
      const int yl = t&31, c = t>>5;
      for(int yc=0; yc<4; yc++){
        int y = yc*32+yl;
        float ar=0.f, ai=0.f;
        for(int n=0;n<128;n++){
          float zv = V2p[y*132+n];
          float2 cs = CS[c*128+n];
          ar += zv*cs.x; ai -= zv*cs.y;
        }
        V[y*17+c] = make_float2(ar, ai);
      }
    }
    __syncthreads();
    {  // stage 2
      int idx = t;
      int r = idx>>4, c = idx&15;
      int ky = (r<16)? r : 96+r;
      float hr=0.f, hi=0.f;
      for(int y=0;y<128;y++){
        float2 Rv = V[y*17+c];
        float2 cs = CS[128 + ((ky*y)&127)];
        hr += Rv.x*cs.x + Rv.y*cs.y;
        hi += Rv.y*cs.x - Rv.x*cs.y;
      }
      HcOut[mmap*512+idx] = make_float2(hr*(1.0f/16384.0f), hi*(1.0f/16384.0f));
    }
  }
}

extern "C" void kernel_launch(void* const* d_in, const int* in_sizes, int n_in,
                              void* d_out, int out_size, void* d_ws, size_t ws_size,
                              hipStream_t stream)
{
  const float* x        = (const float*)d_in[0];
  const float* norm1_w  = (const float*)d_in[1];
  const float* norm1_b  = (const float*)d_in[2];
  const float* kqv_wr   = (const float*)d_in[3];
  const float* kqv_wi   = (const float*)d_in[4];
  const float* kqv_bias = (const float*)d_in[5];
  const float* kqv_sw   = (const float*)d_in[6];
  const float* kqv_sb   = (const float*)d_in[7];
  const float* p_wr     = (const float*)d_in[8];
  const float* p_wi     = (const float*)d_in[9];
  const float* p_bias   = (const float*)d_in[10];
  const float* p_sw     = (const float*)d_in[11];
  const float* p_sb     = (const float*)d_in[12];
  const float* attn_norm_w = (const float*)d_in[13];
  const float* attn_norm_b = (const float*)d_in[14];
  const float* norm2_w  = (const float*)d_in[15];
  const float* norm2_b  = (const float*)d_in[16];
  const float* mix_wr   = (const float*)d_in[17];
  const float* mix_wi   = (const float*)d_in[18];
  // mix_bias (d_in[19]) only shifts the spectral mean which IN removes -> unused
  const float* mix_sw   = (const float*)d_in[20];
  const float* mix_sb   = (const float*)d_in[21];
  const float* mon_w    = (const float*)d_in[22];
  const float* mon_b    = (const float*)d_in[23];
  float* out = (float*)d_out;

  const size_t NEED = (size_t)26576128 * sizeof(float);
  if(ws_size < NEED) return;

  float* ws = (float*)d_ws;
  size_t off = 0;
  float2* CS  = (float2*)(ws + off); off += 32768;
  float* a1   = ws + off; off += 256;
  float* b1   = ws + off; off += 256;
  float* a2   = ws + off; off += 256;
  float* b2   = ws + off; off += 256;
  float* pbeta= ws + off; off += 256;
  float2* Xt2 = (float2*)(ws + off); off += 1081344;
  float* pool = ws + off; off += 17301504;
  float* P    = ws + off; off += 262144;
  float* PAT  = ws + off; off += 32768;
  float2* Xp  = (float2*)(ws + off); off += 262144;
  float* Zc_unused = ws + off; off += 2097152;   // kept for layout stability
  float2* Bc  = (float2*)(ws + off); off += 262144;
  float* attn = ws + off; off += 4194304;
  float2* Hc  = (float2*)(ws + off); off += 524288;
  float2* Sn  = (float2*)(ws + off); off += 524288;
  (void)Zc_unused;

  float* Pp   = attn;                  // 16 x 262144 partials, dead before epi0

  // pool slots
  float2* Kc = (float2*)pool;                      // 8650752 floats (4325376 cplx)
  float* y0g = pool;                   // after softmax (Kc dead)
  float* h1  = pool + 4325376;

  k_tables<<<dim3(128), dim3(128), 0, stream>>>(CS);
  k_instats<<<dim3(256), dim3(256), 0, stream>>>(x, norm1_w, norm1_b, a1, b1);
  k_spec<<<dim3(256), dim3(512), 0, stream>>>(x, CS, a1, norm1_b,
                                              kqv_wr, kqv_wi, kqv_bias, kqv_sw, kqv_sb,
                                              Xt2, Xp, Kc);
  k_scores<<<dim3(1024), dim3(256), 0, stream>>>(Xt2, Kc, Pp);
  k_softmax<<<dim3(2048), dim3(64), 0, stream>>>(Pp, P);
  k_peff<<<dim3(128), dim3(256), 0, stream>>>(P, p_sw, kqv_sw, a1, PAT);
  k_pbeta<<<dim3(256), dim3(128), 0, stream>>>(P, p_sw, kqv_sw, b1, pbeta);
  k_zcorr<<<dim3(256), dim3(512), 0, stream>>>(P, Xp, kqv_wr, kqv_wi, kqv_bias, kqv_sw, kqv_sb,
                                               p_wr, p_wi, p_bias, p_sw, p_sb, Bc);
  k_attn_gemm<<<dim3(512), dim3(256), 0, stream>>>(PAT, x, pbeta, y0g);
  k_epi0<<<dim3(256), dim3(512), 0, stream>>>(y0g, x, Bc, CS, attn_norm_w, attn_norm_b,
                                              norm2_w, norm2_b, attn, a2, b2, Hc);
  // mixer layer 1 (mixinv emits h1 + Hc(h1))
  k_mixc<<<dim3(256), dim3(256), 0, stream>>>(Hc, mix_wr, mix_wi, Sn);
  k_mixinv<<<dim3(256), dim3(512), 0, stream>>>(Sn, attn, a2, b2, mix_sw, mix_sb, CS, 1,
                                                Hc, (const float*)nullptr,
                                                (const float*)nullptr, (const float*)nullptr, h1);
  // mixer layer 2 (mixinv absorbs epi2: final IN + attn add -> out)
  k_mixc<<<dim3(256), dim3(256), 0, stream>>>(Hc, mix_wr+8192, mix_wi+8192, Sn);
  k_mixinv<<<dim3(256), dim3(512), 0, stream>>>(Sn, h1, (const float*)nullptr, (const float*)nullptr,
                                                mix_sw+16, mix_sb+4, CS, 0,
                                                (float2*)nullptr, attn, mon_w, mon_b, out);
}

// Round 13
// 386.339 us; speedup vs baseline: 1.1509x; 1.1509x over previous
//
#include <hip/hip_runtime.h>
#include <math.h>

// TNO block, round 13: revert k_spec (occupancy collapse) to split p1/p2/build_k
// (round-11 proven versions); keep k_zcorr fusion from round 12.
// Spectra: forward-normalized, x[y][n] = sum A e^{+2pi i(ky y+kx n)/128}.

#define NT 2112   // 64*33 truncated spectrum per map

__device__ __forceinline__ void blockReduce2(float& a, float& b, float* red){
  const int tid = threadIdx.x, n = blockDim.x;
  red[tid] = a; red[n+tid] = b;
  __syncthreads();
  for(int off=n>>1; off>0; off>>=1){
    if(tid<off){ red[tid]+=red[tid+off]; red[n+tid]+=red[n+tid+off]; }
    __syncthreads();
  }
  a = red[0]; b = red[n];
  __syncthreads();
}

__device__ __forceinline__ float2 cmul_add(float2 acc, float2 w, float2 x){
  acc.x += w.x*x.x - w.y*x.y;
  acc.y += w.x*x.y + w.y*x.x;
  return acc;
}

// ---------------- twiddle table: CS[a*128+b] = (cos,sin)(2pi a b/128) ----------
__global__ void k_tables(float2* __restrict__ CS){
  int a = blockIdx.x, b = threadIdx.x;
  int p = (a*b)&127;
  float t = (float)p * (1.0f/64.0f);
  CS[a*128+b] = make_float2(cospif(t), sinpif(t));
}

// ---------------- per-map IN stats of x: alpha1 = w*rs, beta1 = b - mu*alpha ---
__global__ __launch_bounds__(256) void k_instats(
    const float* __restrict__ xin, const float* __restrict__ n1w,
    const float* __restrict__ n1b, float* __restrict__ a1, float* __restrict__ b1)
{
  __shared__ float red[512];
  const int m = blockIdx.x, t = threadIdx.x;
  const float* xp = xin + (size_t)m*16384;
  float s1=0.f, s2=0.f;
  for(int i=t;i<4096;i+=256){
    float4 v = ((const float4*)xp)[i];
    s1 += v.x+v.y+v.z+v.w;
    s2 += v.x*v.x+v.y*v.y+v.z*v.z+v.w*v.w;
  }
  blockReduce2(s1,s2,red);
  if(t==0){
    float mu = s1*(1.0f/16384.0f);
    float var = s2*(1.0f/16384.0f)-mu*mu;
    float a = n1w[0]*rsqrtf(var+1e-5f);
    a1[m] = a; b1[m] = n1b[0] - mu*a;
  }
}

// ---------------- k_p1: x-dim partial DFT (33 cols): R[y][c] -------------------
__global__ __launch_bounds__(256) void k_p1(
    const float* __restrict__ xin, float* __restrict__ R1r, float* __restrict__ R1i,
    const float2* __restrict__ CS)
{
  __shared__ float xl[32*129];
  __shared__ float2 csl[4224];
  const int bid = blockIdx.x;
  const int m = bid>>2, yt = bid&3;
  const int t = threadIdx.x;
  for(int i=t;i<4224;i+=256) csl[i] = CS[i];
  {
    const float4* xp4 = (const float4*)(xin + (size_t)m*16384 + yt*4096);
    for(int i4=t;i4<1024;i4+=256){
      float4 v = xp4[i4];
      int y = i4>>5, n = (i4&31)*4;
      xl[y*129+n]=v.x; xl[y*129+n+1]=v.y; xl[y*129+n+2]=v.z; xl[y*129+n+3]=v.w;
    }
  }
  __syncthreads();
  const int yl = t&31, cg = t>>5;
  const int nc = (cg==0)?5:4;
  float ar[5]={0,0,0,0,0}, ai[5]={0,0,0,0,0};
  for(int n=0;n<128;n++){
    float xv = xl[yl*129+n];
    #pragma unroll
    for(int k=0;k<5;k++){
      if(k<nc){
        float2 cs = csl[(cg+8*k)*128+n];
        ar[k] += xv*cs.x;
        ai[k] -= xv*cs.y;
      }
    }
  }
  __syncthreads();
  #pragma unroll
  for(int k=0;k<5;k++){
    if(k<nc){
      int c = cg+8*k;
      xl[yl*33+c] = ar[k];
      xl[1056 + yl*33+c] = ai[k];
    }
  }
  __syncthreads();
  const int gb = m*4224 + yt*1056;
  for(int idx=t; idx<2112; idx+=256){
    if(idx<1056) R1r[gb+idx] = xl[idx];
    else         R1i[gb+idx-1056] = xl[idx];
  }
}

// ---------------- k_p2: y-dim DFT -> Xt2[r*33+c] (+ corner gather Xp) ----------
__global__ __launch_bounds__(704) void k_p2(
    const float* __restrict__ R1r, const float* __restrict__ R1i,
    const float2* __restrict__ CS, const float* __restrict__ a1,
    const float* __restrict__ n1b,
    float2* __restrict__ Xt2, float2* __restrict__ Xp)
{
  __shared__ float2 Rl[128*34];
  const int m = blockIdx.x, t = threadIdx.x;
  for(int idx=t; idx<4224; idx+=704){
    int y = idx/33, c = idx - y*33;
    Rl[y*34+c] = make_float2(R1r[m*4224+idx], R1i[m*4224+idx]);
  }
  __syncthreads();
  const float sc = a1[m]*(1.0f/16384.0f);
  const int r = t&63;
  const int ky = (r<32)? r : r+64;
  #pragma unroll
  for(int k=0;k<3;k++){
    int c = (t>>6) + 11*k;
    float ar=0.f, ai=0.f;
    for(int y=0;y<128;y++){
      float2 Rv = Rl[y*34+c];            // wave-uniform broadcast
      float2 cs = CS[128 + ((ky*y)&127)];
      ar += Rv.x*cs.x + Rv.y*cs.y;
      ai += Rv.y*cs.x - Rv.x*cs.y;
    }
    int j = r*33 + c;
    float vr = ar*sc, vi = ai*sc;
    if(j==0){ vr = n1b[0]; vi = 0.f; }
    Xt2[m*NT+j] = make_float2(vr, vi);
    if(c<16 && (r<16 || r>=48)){
      int rp = (r<16)? r : r-32;
      Xp[m*512 + rp*16 + c] = make_float2(vr, vi);
    }
  }
}

// ---------------- K'' build: K'' = wsc * conj(A) * Pi(B*X), DC zeroed ----------
__global__ __launch_bounds__(256) void k_build_k(
  const float2* __restrict__ Xt2,
  const float* __restrict__ kqv_wr, const float* __restrict__ kqv_wi,
  const float* __restrict__ kqv_bias, const float* __restrict__ kqv_sw,
  const float* __restrict__ kqv_sb,
  float2* __restrict__ Kc)
{
  __shared__ float2 T[2112];
  __shared__ float2 Ks[2112];
  const int bid = blockIdx.x;
  const int m = bid & 255, o = bid >> 8;
  const int tid = threadIdx.x;
  for(int j=tid;j<2112;j+=256) T[j] = Xt2[m*NT+j];
  __syncthreads();
  const float swK = kqv_sw[o];
  const float swQ = kqv_sw[8+o];
  for(int j=tid;j<2112;j+=256){
    int r = j/33, c = j - r*33;
    float2 X = T[j];
    float2 K = make_float2(swK*X.x, swK*X.y);
    if(c<8){
      int wrow = (r<8)? r : ((r>=56)? r-48 : -1);
      if(wrow>=0)
        K = cmul_add(K, make_float2(kqv_wr[(o*16+wrow)*8+c], kqv_wi[(o*16+wrow)*8+c]), X);
    }
    if(j==0) K.x += kqv_bias[o] + kqv_sb[o];
    Ks[j] = K;
  }
  __syncthreads();
  const size_t ob = ((size_t)(m*8+o))*NT;
  for(int j=tid;j<2112;j+=256){
    int r = j/33, c = j - r*33;
    float2 K = Ks[j];
    float wsc = 128.0f;
    if(c==0 || c==32){
      int pj = ((64-r)&63)*33 + c;
      float2 K2 = Ks[pj];
      K = make_float2(0.5f*(K.x+K2.x), 0.5f*(K.y-K2.y));
      wsc = 64.0f;
    }
    float ar = swQ, ai = 0.f;
    if(c<8){
      int wrow = (r<8)? r : ((r>=56)? r-48 : -1);
      if(wrow>=0){ ar += kqv_wr[((8+o)*16+wrow)*8+c]; ai += kqv_wi[((8+o)*16+wrow)*8+c]; }
    }
    float2 out = make_float2(wsc*(ar*K.x + ai*K.y), wsc*(ar*K.y - ai*K.x));
    if(j==0) out = make_float2(0.f, 0.f);
    Kc[ob+j] = out;
  }
}

// ---------------- scores SGEMM: Q-side = raw Xt2; 64x64 tiles, 4x4 accs --------
__global__ __launch_bounds__(256) void k_scores(
  const float2* __restrict__ Xt2, const float2* __restrict__ Kc,
  float* __restrict__ Pp)
{
  __shared__ float Qs[64*52];
  __shared__ float Ks[64*52];
  const int bid = blockIdx.x;
  const int fq = bid&15, st = (bid>>4)&1, tt = (bid>>5)&1, h = (bid>>6)&7, b = bid>>9;
  const int t = threadIdx.x;
  const int tg = t>>4, sg = t&15;
  const int t0 = tt*64, s0 = st*64;
  const int f2base = fq*132;
  float acc[4][4];
  #pragma unroll
  for(int i=0;i<4;i++)
    #pragma unroll
    for(int j=0;j<4;j++) acc[i][j]=0.f;
  for(int sub=0; sub<6; sub++){
    __syncthreads();
    const int fo = f2base + sub*22;
    for(int idx=t; idx<1408; idx+=256){
      int rl = idx/22, f2 = idx - rl*22;
      float2 q = Xt2[(size_t)(b*128 + t0+rl)*NT + fo + f2];
      ((float2*)(Qs + rl*52))[f2] = q;
      float2 kk = Kc[((size_t)((b*128 + s0+rl)*8+h))*NT + fo + f2];
      ((float2*)(Ks + rl*52))[f2] = kk;
    }
    __syncthreads();
    #pragma unroll
    for(int f4=0; f4<11; f4++){
      float4 qv[4], kv[4];
      #pragma unroll
      for(int i=0;i<4;i++) qv[i] = *(const float4*)&Qs[(tg+16*i)*52 + f4*4];
      #pragma unroll
      for(int j=0;j<4;j++) kv[j] = *(const float4*)&Ks[(sg+16*j)*52 + f4*4];
      #pragma unroll
      for(int i=0;i<4;i++)
        #pragma unroll
        for(int j=0;j<4;j++)
          acc[i][j] += qv[i].x*kv[j].x + qv[i].y*kv[j].y
                     + qv[i].z*kv[j].z + qv[i].w*kv[j].w;
    }
  }
  #pragma unroll
  for(int i=0;i<4;i++){
    int tg2 = t0 + tg + 16*i;
    #pragma unroll
    for(int j=0;j<4;j++){
      int s = s0 + sg + 16*j;
      Pp[(size_t)fq*262144 + ((size_t)((b*8+h)*128+tg2))*128 + s] = acc[i][j];
    }
  }
}

__global__ __launch_bounds__(64) void k_softmax(const float* __restrict__ Pp,
                                                float* __restrict__ P){
  const int row = blockIdx.x, tid = threadIdx.x;
  size_t o = (size_t)row*128;
  float v0=0.f, v1=0.f;
  #pragma unroll
  for(int q=0;q<16;q++){
    v0 += Pp[(size_t)q*262144 + o + tid];
    v1 += Pp[(size_t)q*262144 + o + tid + 64];
  }
  float mx = fmaxf(v0,v1);
  for(int off=32; off; off>>=1) mx = fmaxf(mx, __shfl_xor(mx, off));
  float e0 = expf(v0-mx), e1 = expf(v1-mx);
  float s = e0+e1;
  for(int off=32; off; off>>=1) s += __shfl_xor(s, off);
  float inv = 1.0f/s;
  P[o+tid] = e0*inv; P[o+tid+64] = e1*inv;
}

// PA^T[b][s][t] = alpha1[b*128+s] * sum_h psw*sv*P[b,h,t,s]
__global__ __launch_bounds__(256) void k_peff(const float* __restrict__ P,
   const float* __restrict__ p_sw, const float* __restrict__ kqv_sw,
   const float* __restrict__ a1, float* __restrict__ PAT)
{
  const int i = blockIdx.x*256 + threadIdx.x;
  const int b = i>>14, rem = i&16383;
  const int tch = rem>>7, s = rem&127;
  float acc=0.f;
  for(int hh=0; hh<8; hh++){
    float a = p_sw[hh]*kqv_sw[16+hh];
    acc += a * P[(((size_t)(b*8+hh))<<14) + rem];
  }
  PAT[((size_t)(b*128+s))*128 + tch] = acc * a1[b*128+s];
}

// pbeta[b*128+t] = sum_s (sum_h psw*sv*P) * beta1[b*128+s]
__global__ __launch_bounds__(128) void k_pbeta(const float* __restrict__ P,
   const float* __restrict__ p_sw, const float* __restrict__ kqv_sw,
   const float* __restrict__ b1, float* __restrict__ pbeta)
{
  __shared__ float red[128];
  const int bid = blockIdx.x;
  const int b = bid>>7, tch = bid&127;
  const int s = threadIdx.x;
  float acc=0.f;
  for(int hh=0; hh<8; hh++){
    float a = p_sw[hh]*kqv_sw[16+hh];
    acc += a * P[((size_t)((b*8+hh)*128+tch))*128 + s];
  }
  acc *= b1[b*128+s];
  red[s] = acc; __syncthreads();
  for(int off=64; off>0; off>>=1){
    if(s<off) red[s]+=red[s+off];
    __syncthreads();
  }
  if(s==0) pbeta[bid] = red[0];
}

// ---------------- k_zcorr: Z (per map, all heads, all 512 modes) + corr --------
__global__ __launch_bounds__(512) void k_zcorr(
  const float* __restrict__ P, const float2* __restrict__ Xp,
  const float* __restrict__ kqv_wr, const float* __restrict__ kqv_wi,
  const float* __restrict__ kqv_bias, const float* __restrict__ kqv_sw, const float* __restrict__ kqv_sb,
  const float* __restrict__ p_wr, const float* __restrict__ p_wi,
  const float* __restrict__ p_bias, const float* __restrict__ p_sw, const float* __restrict__ p_sb,
  float2* __restrict__ Bc)
{
  __shared__ float4 Xs4[4096];        // 64 KB: staged Xp s-tiles; later Zl
  __shared__ float Pl[1024];
  const int m = blockIdx.x;
  const int b = m>>7, cix = m&127;
  const int t = threadIdx.x;
  const int j = t;
  for(int idx=t; idx<1024; idx+=512){
    int o = idx>>7, s = idx&127;
    Pl[idx] = P[((size_t)((b*8+o)*128 + cix))*128 + s];
  }
  float2 z[8];
  #pragma unroll
  for(int o=0;o<8;o++) z[o] = make_float2(0.f,0.f);
  const float2* Xs = (const float2*)Xs4;
  for(int st=0; st<8; st++){
    __syncthreads();
    for(int q=t; q<4096; q+=512){
      int sl = q>>8, f4 = q&255;
      Xs4[q] = ((const float4*)(Xp + (size_t)(b*128 + st*16 + sl)*512))[f4];
    }
    __syncthreads();
    for(int sl=0; sl<16; sl++){
      int s = st*16 + sl;
      float2 xv = Xs[sl*512 + j];
      #pragma unroll
      for(int o=0;o<8;o++){
        float p = Pl[o*128+s];
        z[o].x += p*xv.x; z[o].y += p*xv.y;
      }
    }
  }
  __syncthreads();
  float2* Zl = (float2*)Xs4;
  #pragma unroll
  for(int o=0;o<8;o++) Zl[o*512 + j] = z[o];
  __syncthreads();
  {
    int r = j>>4, c = j&15;
    int ky = (r<16)? r : 96+r;
    float accr=0.f, acci=0.f;
    int rp = -1;
    if(c==0){ int kyp = (128-ky)&127; rp = (kyp<16)? kyp : ((kyp>=112)? kyp-96 : -1); }
    for(int o=0;o<8;o++){
      float2 zv = Zl[o*512 + j];
      float cvr=0.f, cvi=0.f;
      bool inV = (c<8) && (ky<8 || ky>=120);
      if(inV){
        int vrow = (ky<8)? ky : 8+(ky-120);
        float wr = kqv_wr[((16+o)*16+vrow)*8+c], wi = kqv_wi[((16+o)*16+vrow)*8+c];
        cvr = wr*zv.x - wi*zv.y; cvi = wr*zv.y + wi*zv.x;
      }
      float ar = cvr, ai = cvi;
      if(c==0){
        float pvr=0.f, pvi=0.f;
        int kyp = (128-ky)&127;
        bool pInV = (kyp<8 || kyp>=120);
        if(pInV && rp>=0){
          int vrow = (kyp<8)? kyp : 8+(kyp-120);
          float2 z2 = Zl[o*512 + rp*16];
          float wr = kqv_wr[((16+o)*16+vrow)*8], wi = kqv_wi[((16+o)*16+vrow)*8];
          pvr = wr*z2.x - wi*z2.y; pvi = wr*z2.y + wi*z2.x;
        }
        ar = 0.5f*(cvr + pvr);
        ai = 0.5f*(cvi - pvi);
      }
      float sv = kqv_sw[16+o];
      float Dv = kqv_bias[16+o] + kqv_sb[16+o];
      float atr = sv*zv.x + ar + ((j==0)? Dv : 0.f);
      float ati = sv*zv.y + ai;
      float psw = p_sw[o];
      accr += psw*ar;  acci += psw*ai;
      float wpr = p_wr[(o*32+r)*16+c], wpi = p_wi[(o*32+r)*16+c];
      accr += wpr*atr - wpi*ati;
      acci += wpr*ati + wpi*atr;
      if(j==0) accr += psw*Dv;
    }
    if(j==0) accr += p_bias[0] + p_sb[0];
    Bc[m*512+j] = make_float2(accr, acci);
  }
}

// ---------------- attn GEMM: y0g[b,c][p] = sum_s PA^T[s][c] * x[s][p] + pbeta --
__global__ __launch_bounds__(256) void k_attn_gemm(
  const float* __restrict__ PAT, const float* __restrict__ xin,
  const float* __restrict__ pbeta, float* __restrict__ y0g)
{
  __shared__ float PAs[32*33];
  __shared__ float Xs[32*256];
  const int bid = blockIdx.x;
  const int b = bid>>8, ct = (bid>>6)&3, pt = bid&63;
  const int t = threadIdx.x;
  const int tc = t>>6, tp = t&63;
  float4 acc[8];
  #pragma unroll
  for(int k=0;k<8;k++) acc[k] = make_float4(0.f,0.f,0.f,0.f);
  for(int sc4=0; sc4<4; sc4++){
    __syncthreads();
    for(int idx=t; idx<1024; idx+=256){
      int sl = idx>>5, cl = idx&31;
      PAs[sl*33+cl] = PAT[((size_t)(b*128 + sc4*32+sl))*128 + ct*32+cl];
    }
    for(int q=t; q<2048; q+=256){
      int sl = q>>6, p4 = q&63;
      ((float4*)Xs)[q] =
        ((const float4*)xin)[((size_t)(b*128 + sc4*32+sl))*4096 + pt*64 + p4];
    }
    __syncthreads();
    for(int sl=0; sl<32; sl++){
      float4 xv = ((const float4*)Xs)[sl*64+tp];
      #pragma unroll
      for(int k=0;k<8;k++){
        float pa = PAs[sl*33 + tc*8+k];
        acc[k].x += pa*xv.x; acc[k].y += pa*xv.y;
        acc[k].z += pa*xv.z; acc[k].w += pa*xv.w;
      }
    }
  }
  #pragma unroll
  for(int k=0;k<8;k++){
    int c = ct*32 + tc*8 + k;
    float pb = pbeta[b*128+c];
    float4 o = acc[k];
    o.x += pb; o.y += pb; o.z += pb; o.w += pb;
    ((float4*)y0g)[((size_t)(b*128+c))*4096 + pt*64 + tp] = o;
  }
}

// ---------------- epi0 (512 threads): attn = IN(y0g+cinv(Bc)+x)*aw+ab ; + Hc ---
__global__ __launch_bounds__(512) void k_epi0(
  const float* __restrict__ y0g, const float* __restrict__ xin,
  const float2* __restrict__ Bc,
  const float2* __restrict__ CS,
  const float* __restrict__ awp, const float* __restrict__ abp,
  const float* __restrict__ n2w, const float* __restrict__ n2b,
  float* __restrict__ attn, float* __restrict__ a2, float* __restrict__ b2,
  float2* __restrict__ Hc)
{
  __shared__ float2 Bcl[512];
  __shared__ float2 V[128*17];
  __shared__ float V2p[128*132];
  __shared__ float red[1024];
  const int m = blockIdx.x, t = threadIdx.x;
  Bcl[t] = Bc[m*512+t];
  __syncthreads();
  #pragma unroll
  for(int k=0;k<4;k++){
    int idx = t + 512*k;
    int mm = idx>>4, c = idx&15;
    float vr=0.f, vi=0.f;
    for(int r=0;r<32;r++){
      int ky = (r<16)? r : 96+r;
      float2 bc = Bcl[r*16+c];
      float2 cs = CS[128 + ((ky*mm)&127)];
      vr += bc.x*cs.x - bc.y*cs.y;
      vi += bc.x*cs.y + bc.y*cs.x;
    }
    float w = (c==0)?1.0f:2.0f;
    V[mm*17+c] = make_float2(vr*w, vi*w);
  }
  __syncthreads();
  {
    const int n = t&127, mm0 = t>>7;
    float2 csr[16];
    #pragma unroll
    for(int c=0;c<16;c++) csr[c] = CS[c*128+n];
    for(int k=0;k<32;k++){
      int mm = mm0 + 4*k;
      float cv = 0.f;
      #pragma unroll
      for(int c=0;c<16;c++){
        float2 v2 = V[mm*17+c];
        cv += v2.x*csr[c].x - v2.y*csr[c].y;
      }
      V2p[mm*132+n] = cv;
    }
  }
  __syncthreads();
  const float4* x4 = (const float4*)(xin + (size_t)m*16384);
  const float4* g4 = (const float4*)(y0g + (size_t)m*16384);
  float4* V24 = (float4*)V2p;
  float s1=0.f, s2=0.f;
  for(int k=0;k<8;k++){
    int q = t + 512*k;
    int row = q>>5, c4 = q&31;
    float4 xv = x4[q], gv = g4[q], cc = V24[row*33+c4];
    float4 v;
    v.x = xv.x+gv.x+cc.x; v.y = xv.y+gv.y+cc.y;
    v.z = xv.z+gv.z+cc.z; v.w = xv.w+gv.w+cc.w;
    s1 += v.x+v.y+v.z+v.w;
    s2 += v.x*v.x+v.y*v.y+v.z*v.z+v.w*v.w;
    V24[row*33+c4] = v;
  }
  blockReduce2(s1,s2,red);
  float mu = s1*(1.0f/16384.0f);
  float var = s2*(1.0f/16384.0f)-mu*mu;
  float rs = rsqrtf(var+1e-5f);
  float aw = awp[0], ab = abp[0];
  float4* at4 = (float4*)(attn + (size_t)m*16384);
  for(int k=0;k<8;k++){
    int q = t + 512*k;
    int row = q>>5, c4 = q&31;
    float4 v = V24[row*33+c4];
    float4 ov;
    ov.x = (v.x-mu)*rs*aw + ab;
    ov.y = (v.y-mu)*rs*aw + ab;
    ov.z = (v.z-mu)*rs*aw + ab;
    ov.w = (v.w-mu)*rs*aw + ab;
    at4[q] = ov;
  }
  float va = aw*aw*var/(var+1e-5f);
  float al = n2w[m&3]*rsqrtf(va+1e-5f);
  if(t==0){ a2[m] = al; b2[m] = n2b[m&3] - ab*al; }
  __syncthreads();
  {  // corner DFT stage 1
    const int yl = t&31, c = t>>5;
    for(int yc=0; yc<4; yc++){
      int y = yc*32+yl;
      float ar=0.f, ai=0.f;
      for(int n=0;n<128;n++){
        float zv = V2p[y*132+n];
        float2 cs = CS[c*128+n];
        ar += zv*cs.x; ai -= zv*cs.y;
      }
      V[y*17+c] = make_float2(ar, ai);
    }
  }
  __syncthreads();
  {  // stage 2
    const float scl = al*rs*aw*(1.0f/16384.0f);
    int idx = t;
    int r = idx>>4, c = idx&15;
    int ky = (r<16)? r : 96+r;
    float hr=0.f, hi=0.f;
    for(int y=0;y<128;y++){
      float2 Rv = V[y*17+c];
      float2 cs = CS[128 + ((ky*y)&127)];
      hr += Rv.x*cs.x + Rv.y*cs.y;
      hi += Rv.y*cs.x - Rv.x*cs.y;
    }
    float2 o = make_float2(hr*scl, hi*scl);
    if(idx==0) o = make_float2(n2b[m&3], 0.f);
    Hc[m*512+idx] = o;
  }
}

// ---------------- mixer spectral: S = sum_i w.Hc ; IN in freq -> Sn ------------
__global__ __launch_bounds__(256) void k_mixc(
  const float2* __restrict__ Hc,
  const float* __restrict__ wr0, const float* __restrict__ wi0,
  float2* __restrict__ Sn)
{
  __shared__ float2 Sl[512];
  __shared__ float red[512];
  const int mb = blockIdx.x;
  const int g = mb&63, o = mb>>6;
  const int t = threadIdx.x;
  for(int j=t;j<512;j+=256){
    int r = j>>4, c = j&15;
    float ar=0.f, ai=0.f;
    for(int i2=0;i2<4;i2++){
      float2 h = Hc[(g*4+i2)*512 + j];
      float wr = wr0[((i2*4+o)*32+r)*16+c], wi = wi0[((i2*4+o)*32+r)*16+c];
      ar += wr*h.x - wi*h.y; ai += wr*h.y + wi*h.x;
    }
    Sl[j] = make_float2(ar, ai);
  }
  __syncthreads();
  float vs=0.f, dummy=0.f;
  for(int j=t;j<512;j+=256){
    int c=j&15;
    if(c>=1) vs += 2.0f*(Sl[j].x*Sl[j].x + Sl[j].y*Sl[j].y);
  }
  if(t<32){
    int ky = (t<16)? (t+1) : (96+t);
    float ar=0.f, ai=0.f;
    if(ky<16){ ar=Sl[ky*16].x; ai=Sl[ky*16].y; }
    else if(ky>=112){ int r=ky-96; ar=Sl[r*16].x; ai=Sl[r*16].y; }
    int kyp = 128-ky;
    float br2=0.f, bi2=0.f;
    if(kyp<16){ br2=Sl[kyp*16].x; bi2=Sl[kyp*16].y; }
    else if(kyp>=112){ int r=kyp-96; br2=Sl[r*16].x; bi2=Sl[r*16].y; }
    float pr = 0.5f*(ar+br2), pi = 0.5f*(ai-bi2);
    vs += pr*pr + pi*pi;
  }
  blockReduce2(vs, dummy, red);
  float rs2 = rsqrtf(vs + 1e-5f);
  for(int j=t;j<512;j+=256){
    float2 s = Sl[j];
    if(j==0) Sn[(g*4+o)*512+j] = make_float2(0.f,0.f);
    else     Sn[(g*4+o)*512+j] = make_float2(s.x*rs2, s.y*rs2);
  }
}

// ---------------- mixer inverse (512 threads; +opt Hc emit / final IN+add) -----
__global__ __launch_bounds__(512) void k_mixinv(
  const float2* __restrict__ Sn, const float* __restrict__ inmaps,
  const float* __restrict__ a2, const float* __restrict__ b2,
  const float* __restrict__ msw, const float* __restrict__ msb,
  const float2* __restrict__ CS, const int dogelu,
  float2* __restrict__ HcOut,
  const float* __restrict__ addsrc, const float* __restrict__ mw,
  const float* __restrict__ mbv,
  float* __restrict__ outp)
{
  __shared__ float2 Sl[512];
  __shared__ float2 V[128*17];
  __shared__ float V2p[128*132];
  __shared__ float red[1024];
  const int mb = blockIdx.x;
  const int g = mb&63, o = mb>>6;
  const int mmap = g*4+o;
  const int t = threadIdx.x;
  float cw[4]; float cb = msb[o];
  #pragma unroll
  for(int i=0;i<4;i++){
    float al = a2 ? a2[g*4+i] : 1.0f;
    float be = b2 ? b2[g*4+i] : 0.0f;
    float sw = msw[o*4+i];
    cw[i] = sw*al; cb += sw*be;
  }
  Sl[t] = Sn[mmap*512+t];
  __syncthreads();
  #pragma unroll
  for(int k=0;k<4;k++){
    int idx = t + 512*k;
    int mm = idx>>4, c = idx&15;
    float vr=0.f, vi=0.f;
    for(int r=0;r<32;r++){
      int ky = (r<16)? r : 96+r;
      float2 bc = Sl[r*16+c];
      float2 cs = CS[128 + ((ky*mm)&127)];
      vr += bc.x*cs.x - bc.y*cs.y;
      vi += bc.x*cs.y + bc.y*cs.x;
    }
    float w = (c==0)?1.0f:2.0f;
    V[mm*17+c] = make_float2(vr*w, vi*w);
  }
  __syncthreads();
  {
    const int n = t&127, mm0 = t>>7;
    float2 csr[16];
    #pragma unroll
    for(int c=0;c<16;c++) csr[c] = CS[c*128+n];
    for(int k=0;k<32;k++){
      int mm = mm0 + 4*k;
      float cv = 0.f;
      #pragma unroll
      for(int c=0;c<16;c++){
        float2 v2 = V[mm*17+c];
        cv += v2.x*csr[c].x - v2.y*csr[c].y;
      }
      V2p[mm*132+n] = cv;
    }
  }
  __syncthreads();
  const float4* in4 = (const float4*)(inmaps + (size_t)(g*4)*16384);
  float4* V24 = (float4*)V2p;
  float4* o4 = (float4*)(outp + (size_t)mmap*16384);
  float s1=0.f, s2=0.f;
  for(int k=0;k<8;k++){
    int q = t + 512*k;
    int row = q>>5, c4 = q&31;
    float4 v0 = in4[q], v1 = in4[4096+q], v2 = in4[8192+q], v3 = in4[12288+q];
    float4 cc = V24[row*33+c4];
    float4 ov;
    ov.x = cb + cw[0]*v0.x + cw[1]*v1.x + cw[2]*v2.x + cw[3]*v3.x + cc.x;
    ov.y = cb + cw[0]*v0.y + cw[1]*v1.y + cw[2]*v2.y + cw[3]*v3.y + cc.y;
    ov.z = cb + cw[0]*v0.z + cw[1]*v1.z + cw[2]*v2.z + cw[3]*v3.z + cc.z;
    ov.w = cb + cw[0]*v0.w + cw[1]*v1.w + cw[2]*v2.w + cw[3]*v3.w + cc.w;
    if(dogelu){
      ov.x = 0.5f*ov.x*(1.0f+erff(ov.x*0.70710678118f));
      ov.y = 0.5f*ov.y*(1.0f+erff(ov.y*0.70710678118f));
      ov.z = 0.5f*ov.z*(1.0f+erff(ov.z*0.70710678118f));
      ov.w = 0.5f*ov.w*(1.0f+erff(ov.w*0.70710678118f));
    }
    if(addsrc){
      s1 += ov.x+ov.y+ov.z+ov.w;
      s2 += ov.x*ov.x+ov.y*ov.y+ov.z*ov.z+ov.w*ov.w;
      V24[row*33+c4] = ov;
    } else {
      o4[q] = ov;
      if(HcOut) V24[row*33+c4] = ov;
    }
  }
  if(addsrc){
    blockReduce2(s1,s2,red);
    float mu = s1*(1.0f/16384.0f);
    float var = s2*(1.0f/16384.0f)-mu*mu;
    float rs = rsqrtf(var+1e-5f);
    float w = mw[o], b = mbv[o];
    const float4* a4 = (const float4*)(addsrc + (size_t)mmap*16384);
    for(int k=0;k<8;k++){
      int q = t + 512*k;
      int row = q>>5, c4 = q&31;
      float4 v = V24[row*33+c4], av = a4[q];
      float4 ov;
      ov.x = (v.x-mu)*rs*w + b + av.x;
      ov.y = (v.y-mu)*rs*w + b + av.y;
      ov.z = (v.z-mu)*rs*w + b + av.z;
      ov.w = (v.w-mu)*rs*w + b + av.w;
      o4[q] = ov;
    }
  }
  if(HcOut){
    __syncthreads();
    {  // stage 1 (V reused as Rc)
      const int yl = t&31, c = t>>5;
      for(int yc=0; yc<4; yc++){
        int y = yc*32+yl;
        float ar=0.f, ai=0.f;
        for(int n=0;n<128;n++){
          float zv = V2p[y*132+n];
          float2 cs = CS[c*128+n];
          ar += zv*cs.x; ai -= zv*cs.y;
        }
        V[y*17+c] = make_float2(ar, ai);
      }
    }
    __syncthreads();
    {  // stage 2
      int idx = t;
      int r = idx>>4, c = idx&15;
      int ky = (r<16)? r : 96+r;
      float hr=0.f, hi=0.f;
      for(int y=0;y<128;y++){
        float2 Rv = V[y*17+c];
        float2 cs = CS[128 + ((ky*y)&127)];
        hr += Rv.x*cs.x + Rv.y*cs.y;
        hi += Rv.y*cs.x - Rv.x*cs.y;
      }
      HcOut[mmap*512+idx] = make_float2(hr*(1.0f/16384.0f), hi*(1.0f/16384.0f));
    }
  }
}

extern "C" void kernel_launch(void* const* d_in, const int* in_sizes, int n_in,
                              void* d_out, int out_size, void* d_ws, size_t ws_size,
                              hipStream_t stream)
{
  const float* x        = (const float*)d_in[0];
  const float* norm1_w  = (const float*)d_in[1];
  const float* norm1_b  = (const float*)d_in[2];
  const float* kqv_wr   = (const float*)d_in[3];
  const float* kqv_wi   = (const float*)d_in[4];
  const float* kqv_bias = (const float*)d_in[5];
  const float* kqv_sw   = (const float*)d_in[6];
  const float* kqv_sb   = (const float*)d_in[7];
  const float* p_wr     = (const float*)d_in[8];
  const float* p_wi     = (const float*)d_in[9];
  const float* p_bias   = (const float*)d_in[10];
  const float* p_sw     = (const float*)d_in[11];
  const float* p_sb     = (const float*)d_in[12];
  const float* attn_norm_w = (const float*)d_in[13];
  const float* attn_norm_b = (const float*)d_in[14];
  const float* norm2_w  = (const float*)d_in[15];
  const float* norm2_b  = (const float*)d_in[16];
  const float* mix_wr   = (const float*)d_in[17];
  const float* mix_wi   = (const float*)d_in[18];
  // mix_bias (d_in[19]) only shifts the spectral mean which IN removes -> unused
  const float* mix_sw   = (const float*)d_in[20];
  const float* mix_sb   = (const float*)d_in[21];
  const float* mon_w    = (const float*)d_in[22];
  const float* mon_b    = (const float*)d_in[23];
  float* out = (float*)d_out;

  const size_t NEED = (size_t)26576128 * sizeof(float);
  if(ws_size < NEED) return;

  float* ws = (float*)d_ws;
  size_t off = 0;
  float2* CS  = (float2*)(ws + off); off += 32768;
  float* a1   = ws + off; off += 256;
  float* b1   = ws + off; off += 256;
  float* a2   = ws + off; off += 256;
  float* b2   = ws + off; off += 256;
  float* pbeta= ws + off; off += 256;
  float2* Xt2 = (float2*)(ws + off); off += 1081344;
  float* pool = ws + off; off += 17301504;
  float* P    = ws + off; off += 262144;
  float* PAT  = ws + off; off += 32768;
  float2* Xp  = (float2*)(ws + off); off += 262144;
  float* Zc_unused = ws + off; off += 2097152;   // kept for layout stability
  float2* Bc  = (float2*)(ws + off); off += 262144;
  float* attn = ws + off; off += 4194304;
  float2* Hc  = (float2*)(ws + off); off += 524288;
  float2* Sn  = (float2*)(ws + off); off += 524288;
  (void)Zc_unused;

  float* Pp   = attn;                  // 16 x 262144 partials, dead before epi0

  // pool slots
  float2* Kc = (float2*)pool;                      // 8650752 floats (4325376 cplx)
  float* R1r = pool + 8650752;         // dead after k_p2 (disjoint from Kc)
  float* R1i = pool + 8650752 + 1081344;
  float* y0g = pool;                   // after softmax (Kc dead)
  float* h1  = pool + 4325376;

  k_tables<<<dim3(128), dim3(128), 0, stream>>>(CS);
  k_instats<<<dim3(256), dim3(256), 0, stream>>>(x, norm1_w, norm1_b, a1, b1);
  k_p1<<<dim3(1024), dim3(256), 0, stream>>>(x, R1r, R1i, CS);
  k_p2<<<dim3(256), dim3(704), 0, stream>>>(R1r, R1i, CS, a1, norm1_b, Xt2, Xp);
  k_build_k<<<dim3(2048), dim3(256), 0, stream>>>(Xt2, kqv_wr, kqv_wi, kqv_bias,
                                                  kqv_sw, kqv_sb, Kc);
  k_scores<<<dim3(1024), dim3(256), 0, stream>>>(Xt2, Kc, Pp);
  k_softmax<<<dim3(2048), dim3(64), 0, stream>>>(Pp, P);
  k_peff<<<dim3(128), dim3(256), 0, stream>>>(P, p_sw, kqv_sw, a1, PAT);
  k_pbeta<<<dim3(256), dim3(128), 0, stream>>>(P, p_sw, kqv_sw, b1, pbeta);
  k_zcorr<<<dim3(256), dim3(512), 0, stream>>>(P, Xp, kqv_wr, kqv_wi, kqv_bias, kqv_sw, kqv_sb,
                                               p_wr, p_wi, p_bias, p_sw, p_sb, Bc);
  k_attn_gemm<<<dim3(512), dim3(256), 0, stream>>>(PAT, x, pbeta, y0g);
  k_epi0<<<dim3(256), dim3(512), 0, stream>>>(y0g, x, Bc, CS, attn_norm_w, attn_norm_b,
                                              norm2_w, norm2_b, attn, a2, b2, Hc);
  // mixer layer 1 (mixinv emits h1 + Hc(h1))
  k_mixc<<<dim3(256), dim3(256), 0, stream>>>(Hc, mix_wr, mix_wi, Sn);
  k_mixinv<<<dim3(256), dim3(512), 0, stream>>>(Sn, attn, a2, b2, mix_sw, mix_sb, CS, 1,
                                                Hc, (const float*)nullptr,
                                                (const float*)nullptr, (const float*)nullptr, h1);
  // mixer layer 2 (mixinv absorbs epi2: final IN + attn add -> out)
  k_mixc<<<dim3(256), dim3(256), 0, stream>>>(Hc, mix_wr+8192, mix_wi+8192, Sn);
  k_mixinv<<<dim3(256), dim3(512), 0, stream>>>(Sn, h1, (const float*)nullptr, (const float*)nullptr,
                                                mix_sw+16, mix_sb+4, CS, 0,
                                                (float2*)nullptr, attn, mon_w, mon_b, out);
}

// Round 14
// 376.150 us; speedup vs baseline: 1.1821x; 1.0271x over previous
//
#include <hip/hip_runtime.h>
#include <math.h>

// TNO block, round 14: round-13 + (a) mixc fused into mixinv (per-group Sn built
// in-LDS; HcOut goes to a second buffer to avoid cross-block races), (b) epi0 and
// mixinv widened to 1024 threads (4 waves/SIMD at 1-block/CU LDS footprint).
// Spectra: forward-normalized, x[y][n] = sum A e^{+2pi i(ky y+kx n)/128}.

#define NT 2112   // 64*33 truncated spectrum per map

__device__ __forceinline__ void blockReduce2(float& a, float& b, float* red){
  const int tid = threadIdx.x, n = blockDim.x;
  red[tid] = a; red[n+tid] = b;
  __syncthreads();
  for(int off=n>>1; off>0; off>>=1){
    if(tid<off){ red[tid]+=red[tid+off]; red[n+tid]+=red[n+tid+off]; }
    __syncthreads();
  }
  a = red[0]; b = red[n];
  __syncthreads();
}

__device__ __forceinline__ float2 cmul_add(float2 acc, float2 w, float2 x){
  acc.x += w.x*x.x - w.y*x.y;
  acc.y += w.x*x.y + w.y*x.x;
  return acc;
}

// ---------------- twiddle table: CS[a*128+b] = (cos,sin)(2pi a b/128) ----------
__global__ void k_tables(float2* __restrict__ CS){
  int a = blockIdx.x, b = threadIdx.x;
  int p = (a*b)&127;
  float t = (float)p * (1.0f/64.0f);
  CS[a*128+b] = make_float2(cospif(t), sinpif(t));
}

// ---------------- per-map IN stats of x: alpha1 = w*rs, beta1 = b - mu*alpha ---
__global__ __launch_bounds__(256) void k_instats(
    const float* __restrict__ xin, const float* __restrict__ n1w,
    const float* __restrict__ n1b, float* __restrict__ a1, float* __restrict__ b1)
{
  __shared__ float red[512];
  const int m = blockIdx.x, t = threadIdx.x;
  const float* xp = xin + (size_t)m*16384;
  float s1=0.f, s2=0.f;
  for(int i=t;i<4096;i+=256){
    float4 v = ((const float4*)xp)[i];
    s1 += v.x+v.y+v.z+v.w;
    s2 += v.x*v.x+v.y*v.y+v.z*v.z+v.w*v.w;
  }
  blockReduce2(s1,s2,red);
  if(t==0){
    float mu = s1*(1.0f/16384.0f);
    float var = s2*(1.0f/16384.0f)-mu*mu;
    float a = n1w[0]*rsqrtf(var+1e-5f);
    a1[m] = a; b1[m] = n1b[0] - mu*a;
  }
}

// ---------------- k_p1: x-dim partial DFT (33 cols): R[y][c] -------------------
__global__ __launch_bounds__(256) void k_p1(
    const float* __restrict__ xin, float* __restrict__ R1r, float* __restrict__ R1i,
    const float2* __restrict__ CS)
{
  __shared__ float xl[32*129];
  __shared__ float2 csl[4224];
  const int bid = blockIdx.x;
  const int m = bid>>2, yt = bid&3;
  const int t = threadIdx.x;
  for(int i=t;i<4224;i+=256) csl[i] = CS[i];
  {
    const float4* xp4 = (const float4*)(xin + (size_t)m*16384 + yt*4096);
    for(int i4=t;i4<1024;i4+=256){
      float4 v = xp4[i4];
      int y = i4>>5, n = (i4&31)*4;
      xl[y*129+n]=v.x; xl[y*129+n+1]=v.y; xl[y*129+n+2]=v.z; xl[y*129+n+3]=v.w;
    }
  }
  __syncthreads();
  const int yl = t&31, cg = t>>5;
  const int nc = (cg==0)?5:4;
  float ar[5]={0,0,0,0,0}, ai[5]={0,0,0,0,0};
  for(int n=0;n<128;n++){
    float xv = xl[yl*129+n];
    #pragma unroll
    for(int k=0;k<5;k++){
      if(k<nc){
        float2 cs = csl[(cg+8*k)*128+n];
        ar[k] += xv*cs.x;
        ai[k] -= xv*cs.y;
      }
    }
  }
  __syncthreads();
  #pragma unroll
  for(int k=0;k<5;k++){
    if(k<nc){
      int c = cg+8*k;
      xl[yl*33+c] = ar[k];
      xl[1056 + yl*33+c] = ai[k];
    }
  }
  __syncthreads();
  const int gb = m*4224 + yt*1056;
  for(int idx=t; idx<2112; idx+=256){
    if(idx<1056) R1r[gb+idx] = xl[idx];
    else         R1i[gb+idx-1056] = xl[idx];
  }
}

// ---------------- k_p2: y-dim DFT -> Xt2[r*33+c] (+ corner gather Xp) ----------
__global__ __launch_bounds__(704) void k_p2(
    const float* __restrict__ R1r, const float* __restrict__ R1i,
    const float2* __restrict__ CS, const float* __restrict__ a1,
    const float* __restrict__ n1b,
    float2* __restrict__ Xt2, float2* __restrict__ Xp)
{
  __shared__ float2 Rl[128*34];
  const int m = blockIdx.x, t = threadIdx.x;
  for(int idx=t; idx<4224; idx+=704){
    int y = idx/33, c = idx - y*33;
    Rl[y*34+c] = make_float2(R1r[m*4224+idx], R1i[m*4224+idx]);
  }
  __syncthreads();
  const float sc = a1[m]*(1.0f/16384.0f);
  const int r = t&63;
  const int ky = (r<32)? r : r+64;
  #pragma unroll
  for(int k=0;k<3;k++){
    int c = (t>>6) + 11*k;
    float ar=0.f, ai=0.f;
    for(int y=0;y<128;y++){
      float2 Rv = Rl[y*34+c];            // wave-uniform broadcast
      float2 cs = CS[128 + ((ky*y)&127)];
      ar += Rv.x*cs.x + Rv.y*cs.y;
      ai += Rv.y*cs.x - Rv.x*cs.y;
    }
    int j = r*33 + c;
    float vr = ar*sc, vi = ai*sc;
    if(j==0){ vr = n1b[0]; vi = 0.f; }
    Xt2[m*NT+j] = make_float2(vr, vi);
    if(c<16 && (r<16 || r>=48)){
      int rp = (r<16)? r : r-32;
      Xp[m*512 + rp*16 + c] = make_float2(vr, vi);
    }
  }
}

// ---------------- K'' build: K'' = wsc * conj(A) * Pi(B*X), DC zeroed ----------
__global__ __launch_bounds__(256) void k_build_k(
  const float2* __restrict__ Xt2,
  const float* __restrict__ kqv_wr, const float* __restrict__ kqv_wi,
  const float* __restrict__ kqv_bias, const float* __restrict__ kqv_sw,
  const float* __restrict__ kqv_sb,
  float2* __restrict__ Kc)
{
  __shared__ float2 T[2112];
  __shared__ float2 Ks[2112];
  const int bid = blockIdx.x;
  const int m = bid & 255, o = bid >> 8;
  const int tid = threadIdx.x;
  for(int j=tid;j<2112;j+=256) T[j] = Xt2[m*NT+j];
  __syncthreads();
  const float swK = kqv_sw[o];
  const float swQ = kqv_sw[8+o];
  for(int j=tid;j<2112;j+=256){
    int r = j/33, c = j - r*33;
    float2 X = T[j];
    float2 K = make_float2(swK*X.x, swK*X.y);
    if(c<8){
      int wrow = (r<8)? r : ((r>=56)? r-48 : -1);
      if(wrow>=0)
        K = cmul_add(K, make_float2(kqv_wr[(o*16+wrow)*8+c], kqv_wi[(o*16+wrow)*8+c]), X);
    }
    if(j==0) K.x += kqv_bias[o] + kqv_sb[o];
    Ks[j] = K;
  }
  __syncthreads();
  const size_t ob = ((size_t)(m*8+o))*NT;
  for(int j=tid;j<2112;j+=256){
    int r = j/33, c = j - r*33;
    float2 K = Ks[j];
    float wsc = 128.0f;
    if(c==0 || c==32){
      int pj = ((64-r)&63)*33 + c;
      float2 K2 = Ks[pj];
      K = make_float2(0.5f*(K.x+K2.x), 0.5f*(K.y-K2.y));
      wsc = 64.0f;
    }
    float ar = swQ, ai = 0.f;
    if(c<8){
      int wrow = (r<8)? r : ((r>=56)? r-48 : -1);
      if(wrow>=0){ ar += kqv_wr[((8+o)*16+wrow)*8+c]; ai += kqv_wi[((8+o)*16+wrow)*8+c]; }
    }
    float2 out = make_float2(wsc*(ar*K.x + ai*K.y), wsc*(ar*K.y - ai*K.x));
    if(j==0) out = make_float2(0.f, 0.f);
    Kc[ob+j] = out;
  }
}

// ---------------- scores SGEMM: Q-side = raw Xt2; 64x64 tiles, 4x4 accs --------
__global__ __launch_bounds__(256) void k_scores(
  const float2* __restrict__ Xt2, const float2* __restrict__ Kc,
  float* __restrict__ Pp)
{
  __shared__ float Qs[64*52];
  __shared__ float Ks[64*52];
  const int bid = blockIdx.x;
  const int fq = bid&15, st = (bid>>4)&1, tt = (bid>>5)&1, h = (bid>>6)&7, b = bid>>9;
  const int t = threadIdx.x;
  const int tg = t>>4, sg = t&15;
  const int t0 = tt*64, s0 = st*64;
  const int f2base = fq*132;
  float acc[4][4];
  #pragma unroll
  for(int i=0;i<4;i++)
    #pragma unroll
    for(int j=0;j<4;j++) acc[i][j]=0.f;
  for(int sub=0; sub<6; sub++){
    __syncthreads();
    const int fo = f2base + sub*22;
    for(int idx=t; idx<1408; idx+=256){
      int rl = idx/22, f2 = idx - rl*22;
      float2 q = Xt2[(size_t)(b*128 + t0+rl)*NT + fo + f2];
      ((float2*)(Qs + rl*52))[f2] = q;
      float2 kk = Kc[((size_t)((b*128 + s0+rl)*8+h))*NT + fo + f2];
      ((float2*)(Ks + rl*52))[f2] = kk;
    }
    __syncthreads();
    #pragma unroll
    for(int f4=0; f4<11; f4++){
      float4 qv[4], kv[4];
      #pragma unroll
      for(int i=0;i<4;i++) qv[i] = *(const float4*)&Qs[(tg+16*i)*52 + f4*4];
      #pragma unroll
      for(int j=0;j<4;j++) kv[j] = *(const float4*)&Ks[(sg+16*j)*52 + f4*4];
      #pragma unroll
      for(int i=0;i<4;i++)
        #pragma unroll
        for(int j=0;j<4;j++)
          acc[i][j] += qv[i].x*kv[j].x + qv[i].y*kv[j].y
                     + qv[i].z*kv[j].z + qv[i].w*kv[j].w;
    }
  }
  #pragma unroll
  for(int i=0;i<4;i++){
    int tg2 = t0 + tg + 16*i;
    #pragma unroll
    for(int j=0;j<4;j++){
      int s = s0 + sg + 16*j;
      Pp[(size_t)fq*262144 + ((size_t)((b*8+h)*128+tg2))*128 + s] = acc[i][j];
    }
  }
}

__global__ __launch_bounds__(64) void k_softmax(const float* __restrict__ Pp,
                                                float* __restrict__ P){
  const int row = blockIdx.x, tid = threadIdx.x;
  size_t o = (size_t)row*128;
  float v0=0.f, v1=0.f;
  #pragma unroll
  for(int q=0;q<16;q++){
    v0 += Pp[(size_t)q*262144 + o + tid];
    v1 += Pp[(size_t)q*262144 + o + tid + 64];
  }
  float mx = fmaxf(v0,v1);
  for(int off=32; off; off>>=1) mx = fmaxf(mx, __shfl_xor(mx, off));
  float e0 = expf(v0-mx), e1 = expf(v1-mx);
  float s = e0+e1;
  for(int off=32; off; off>>=1) s += __shfl_xor(s, off);
  float inv = 1.0f/s;
  P[o+tid] = e0*inv; P[o+tid+64] = e1*inv;
}

// PA^T[b][s][t] = alpha1[b*128+s] * sum_h psw*sv*P[b,h,t,s]
__global__ __launch_bounds__(256) void k_peff(const float* __restrict__ P,
   const float* __restrict__ p_sw, const float* __restrict__ kqv_sw,
   const float* __restrict__ a1, float* __restrict__ PAT)
{
  const int i = blockIdx.x*256 + threadIdx.x;
  const int b = i>>14, rem = i&16383;
  const int tch = rem>>7, s = rem&127;
  float acc=0.f;
  for(int hh=0; hh<8; hh++){
    float a = p_sw[hh]*kqv_sw[16+hh];
    acc += a * P[(((size_t)(b*8+hh))<<14) + rem];
  }
  PAT[((size_t)(b*128+s))*128 + tch] = acc * a1[b*128+s];
}

// pbeta[b*128+t] = sum_s (sum_h psw*sv*P) * beta1[b*128+s]
__global__ __launch_bounds__(128) void k_pbeta(const float* __restrict__ P,
   const float* __restrict__ p_sw, const float* __restrict__ kqv_sw,
   const float* __restrict__ b1, float* __restrict__ pbeta)
{
  __shared__ float red[128];
  const int bid = blockIdx.x;
  const int b = bid>>7, tch = bid&127;
  const int s = threadIdx.x;
  float acc=0.f;
  for(int hh=0; hh<8; hh++){
    float a = p_sw[hh]*kqv_sw[16+hh];
    acc += a * P[((size_t)((b*8+hh)*128+tch))*128 + s];
  }
  acc *= b1[b*128+s];
  red[s] = acc; __syncthreads();
  for(int off=64; off>0; off>>=1){
    if(s<off) red[s]+=red[s+off];
    __syncthreads();
  }
  if(s==0) pbeta[bid] = red[0];
}

// ---------------- k_zcorr: Z (per map, all heads, all 512 modes) + corr --------
__global__ __launch_bounds__(512) void k_zcorr(
  const float* __restrict__ P, const float2* __restrict__ Xp,
  const float* __restrict__ kqv_wr, const float* __restrict__ kqv_wi,
  const float* __restrict__ kqv_bias, const float* __restrict__ kqv_sw, const float* __restrict__ kqv_sb,
  const float* __restrict__ p_wr, const float* __restrict__ p_wi,
  const float* __restrict__ p_bias, const float* __restrict__ p_sw, const float* __restrict__ p_sb,
  float2* __restrict__ Bc)
{
  __shared__ float4 Xs4[4096];        // 64 KB: staged Xp s-tiles; later Zl
  __shared__ float Pl[1024];
  const int m = blockIdx.x;
  const int b = m>>7, cix = m&127;
  const int t = threadIdx.x;
  const int j = t;
  for(int idx=t; idx<1024; idx+=512){
    int o = idx>>7, s = idx&127;
    Pl[idx] = P[((size_t)((b*8+o)*128 + cix))*128 + s];
  }
  float2 z[8];
  #pragma unroll
  for(int o=0;o<8;o++) z[o] = make_float2(0.f,0.f);
  const float2* Xs = (const float2*)Xs4;
  for(int st=0; st<8; st++){
    __syncthreads();
    for(int q=t; q<4096; q+=512){
      int sl = q>>8, f4 = q&255;
      Xs4[q] = ((const float4*)(Xp + (size_t)(b*128 + st*16 + sl)*512))[f4];
    }
    __syncthreads();
    for(int sl=0; sl<16; sl++){
      int s = st*16 + sl;
      float2 xv = Xs[sl*512 + j];
      #pragma unroll
      for(int o=0;o<8;o++){
        float p = Pl[o*128+s];
        z[o].x += p*xv.x; z[o].y += p*xv.y;
      }
    }
  }
  __syncthreads();
  float2* Zl = (float2*)Xs4;
  #pragma unroll
  for(int o=0;o<8;o++) Zl[o*512 + j] = z[o];
  __syncthreads();
  {
    int r = j>>4, c = j&15;
    int ky = (r<16)? r : 96+r;
    float accr=0.f, acci=0.f;
    int rp = -1;
    if(c==0){ int kyp = (128-ky)&127; rp = (kyp<16)? kyp : ((kyp>=112)? kyp-96 : -1); }
    for(int o=0;o<8;o++){
      float2 zv = Zl[o*512 + j];
      float cvr=0.f, cvi=0.f;
      bool inV = (c<8) && (ky<8 || ky>=120);
      if(inV){
        int vrow = (ky<8)? ky : 8+(ky-120);
        float wr = kqv_wr[((16+o)*16+vrow)*8+c], wi = kqv_wi[((16+o)*16+vrow)*8+c];
        cvr = wr*zv.x - wi*zv.y; cvi = wr*zv.y + wi*zv.x;
      }
      float ar = cvr, ai = cvi;
      if(c==0){
        float pvr=0.f, pvi=0.f;
        int kyp = (128-ky)&127;
        bool pInV = (kyp<8 || kyp>=120);
        if(pInV && rp>=0){
          int vrow = (kyp<8)? kyp : 8+(kyp-120);
          float2 z2 = Zl[o*512 + rp*16];
          float wr = kqv_wr[((16+o)*16+vrow)*8], wi = kqv_wi[((16+o)*16+vrow)*8];
          pvr = wr*z2.x - wi*z2.y; pvi = wr*z2.y + wi*z2.x;
        }
        ar = 0.5f*(cvr + pvr);
        ai = 0.5f*(cvi - pvi);
      }
      float sv = kqv_sw[16+o];
      float Dv = kqv_bias[16+o] + kqv_sb[16+o];
      float atr = sv*zv.x + ar + ((j==0)? Dv : 0.f);
      float ati = sv*zv.y + ai;
      float psw = p_sw[o];
      accr += psw*ar;  acci += psw*ai;
      float wpr = p_wr[(o*32+r)*16+c], wpi = p_wi[(o*32+r)*16+c];
      accr += wpr*atr - wpi*ati;
      acci += wpr*ati + wpi*atr;
      if(j==0) accr += psw*Dv;
    }
    if(j==0) accr += p_bias[0] + p_sb[0];
    Bc[m*512+j] = make_float2(accr, acci);
  }
}

// ---------------- attn GEMM: y0g[b,c][p] = sum_s PA^T[s][c] * x[s][p] + pbeta --
__global__ __launch_bounds__(256) void k_attn_gemm(
  const float* __restrict__ PAT, const float* __restrict__ xin,
  const float* __restrict__ pbeta, float* __restrict__ y0g)
{
  __shared__ float PAs[32*33];
  __shared__ float Xs[32*256];
  const int bid = blockIdx.x;
  const int b = bid>>8, ct = (bid>>6)&3, pt = bid&63;
  const int t = threadIdx.x;
  const int tc = t>>6, tp = t&63;
  float4 acc[8];
  #pragma unroll
  for(int k=0;k<8;k++) acc[k] = make_float4(0.f,0.f,0.f,0.f);
  for(int sc4=0; sc4<4; sc4++){
    __syncthreads();
    for(int idx=t; idx<1024; idx+=256){
      int sl = idx>>5, cl = idx&31;
      PAs[sl*33+cl] = PAT[((size_t)(b*128 + sc4*32+sl))*128 + ct*32+cl];
    }
    for(int q=t; q<2048; q+=256){
      int sl = q>>6, p4 = q&63;
      ((float4*)Xs)[q] =
        ((const float4*)xin)[((size_t)(b*128 + sc4*32+sl))*4096 + pt*64 + p4];
    }
    __syncthreads();
    for(int sl=0; sl<32; sl++){
      float4 xv = ((const float4*)Xs)[sl*64+tp];
      #pragma unroll
      for(int k=0;k<8;k++){
        float pa = PAs[sl*33 + tc*8+k];
        acc[k].x += pa*xv.x; acc[k].y += pa*xv.y;
        acc[k].z += pa*xv.z; acc[k].w += pa*xv.w;
      }
    }
  }
  #pragma unroll
  for(int k=0;k<8;k++){
    int c = ct*32 + tc*8 + k;
    float pb = pbeta[b*128+c];
    float4 o = acc[k];
    o.x += pb; o.y += pb; o.z += pb; o.w += pb;
    ((float4*)y0g)[((size_t)(b*128+c))*4096 + pt*64 + tp] = o;
  }
}

// ---------------- epi0 (1024 threads): attn = IN(y0g+cinv(Bc)+x)*aw+ab ; + Hc --
__global__ __launch_bounds__(1024) void k_epi0(
  const float* __restrict__ y0g, const float* __restrict__ xin,
  const float2* __restrict__ Bc,
  const float2* __restrict__ CS,
  const float* __restrict__ awp, const float* __restrict__ abp,
  const float* __restrict__ n2w, const float* __restrict__ n2b,
  float* __restrict__ attn, float* __restrict__ a2, float* __restrict__ b2,
  float2* __restrict__ Hc)
{
  __shared__ float2 Bcl[512];
  __shared__ float2 V[128*17];
  __shared__ float V2p[128*132];
  __shared__ float red[2048];
  const int m = blockIdx.x, t = threadIdx.x;
  if(t<512) Bcl[t] = Bc[m*512+t];
  __syncthreads();
  #pragma unroll
  for(int k=0;k<2;k++){
    int idx = t + 1024*k;
    int mm = idx>>4, c = idx&15;
    float vr=0.f, vi=0.f;
    for(int r=0;r<32;r++){
      int ky = (r<16)? r : 96+r;
      float2 bc = Bcl[r*16+c];
      float2 cs = CS[128 + ((ky*mm)&127)];
      vr += bc.x*cs.x - bc.y*cs.y;
      vi += bc.x*cs.y + bc.y*cs.x;
    }
    float w = (c==0)?1.0f:2.0f;
    V[mm*17+c] = make_float2(vr*w, vi*w);
  }
  __syncthreads();
  {
    const int n = t&127, mm0 = t>>7;   // mm0 in [0,8)
    float2 csr[16];
    #pragma unroll
    for(int c=0;c<16;c++) csr[c] = CS[c*128+n];
    for(int k=0;k<16;k++){
      int mm = mm0 + 8*k;
      float cv = 0.f;
      #pragma unroll
      for(int c=0;c<16;c++){
        float2 v2 = V[mm*17+c];
        cv += v2.x*csr[c].x - v2.y*csr[c].y;
      }
      V2p[mm*132+n] = cv;
    }
  }
  __syncthreads();
  const float4* x4 = (const float4*)(xin + (size_t)m*16384);
  const float4* g4 = (const float4*)(y0g + (size_t)m*16384);
  float4* V24 = (float4*)V2p;
  float s1=0.f, s2=0.f;
  for(int k=0;k<4;k++){
    int q = t + 1024*k;
    int row = q>>5, c4 = q&31;
    float4 xv = x4[q], gv = g4[q], cc = V24[row*33+c4];
    float4 v;
    v.x = xv.x+gv.x+cc.x; v.y = xv.y+gv.y+cc.y;
    v.z = xv.z+gv.z+cc.z; v.w = xv.w+gv.w+cc.w;
    s1 += v.x+v.y+v.z+v.w;
    s2 += v.x*v.x+v.y*v.y+v.z*v.z+v.w*v.w;
    V24[row*33+c4] = v;
  }
  blockReduce2(s1,s2,red);
  float mu = s1*(1.0f/16384.0f);
  float var = s2*(1.0f/16384.0f)-mu*mu;
  float rs = rsqrtf(var+1e-5f);
  float aw = awp[0], ab = abp[0];
  float4* at4 = (float4*)(attn + (size_t)m*16384);
  for(int k=0;k<4;k++){
    int q = t + 1024*k;
    int row = q>>5, c4 = q&31;
    float4 v = V24[row*33+c4];
    float4 ov;
    ov.x = (v.x-mu)*rs*aw + ab;
    ov.y = (v.y-mu)*rs*aw + ab;
    ov.z = (v.z-mu)*rs*aw + ab;
    ov.w = (v.w-mu)*rs*aw + ab;
    at4[q] = ov;
  }
  float va = aw*aw*var/(var+1e-5f);
  float al = n2w[m&3]*rsqrtf(va+1e-5f);
  if(t==0){ a2[m] = al; b2[m] = n2b[m&3] - ab*al; }
  __syncthreads();
  {  // corner DFT stage 1: 2048 (y,c) tasks, 2 per thread, c quasi-wave-uniform
    const int yl = t&31, c = (t>>5)&15, half = t>>9;
    for(int yc=2*half; yc<2*half+2; yc++){
      int y = yc*32+yl;
      float ar=0.f, ai=0.f;
      for(int n=0;n<128;n++){
        float zv = V2p[y*132+n];
        float2 cs = CS[c*128+n];
        ar += zv*cs.x; ai -= zv*cs.y;
      }
      V[y*17+c] = make_float2(ar, ai);
    }
  }
  __syncthreads();
  if(t<512){  // stage 2
    const float scl = al*rs*aw*(1.0f/16384.0f);
    int idx = t;
    int r = idx>>4, c = idx&15;
    int ky = (r<16)? r : 96+r;
    float hr=0.f, hi=0.f;
    for(int y=0;y<128;y++){
      float2 Rv = V[y*17+c];
      float2 cs = CS[128 + ((ky*y)&127)];
      hr += Rv.x*cs.x + Rv.y*cs.y;
      hi += Rv.y*cs.x - Rv.x*cs.y;
    }
    float2 o = make_float2(hr*scl, hi*scl);
    if(idx==0) o = make_float2(n2b[m&3], 0.f);
    Hc[m*512+idx] = o;
  }
}

// ---------------- mixer (1024 threads): mixc fused + inverse + opt Hc/final ----
__global__ __launch_bounds__(1024) void k_mixinv(
  const float2* __restrict__ Hcin, const float* __restrict__ inmaps,
  const float* __restrict__ a2, const float* __restrict__ b2,
  const float* __restrict__ wr0, const float* __restrict__ wi0,
  const float* __restrict__ msw, const float* __restrict__ msb,
  const float2* __restrict__ CS, const int dogelu,
  float2* __restrict__ HcOut,
  const float* __restrict__ addsrc, const float* __restrict__ mw,
  const float* __restrict__ mbv,
  float* __restrict__ outp)
{
  __shared__ float2 Hcl[2048];
  __shared__ float2 Sl[512];
  __shared__ float2 V[128*17];
  __shared__ float V2p[128*132];
  __shared__ float red[2048];
  const int mb = blockIdx.x;
  const int g = mb&63, o = mb>>6;
  const int mmap = g*4+o;
  const int t = threadIdx.x;
  float cw[4]; float cb = msb[o];
  #pragma unroll
  for(int i=0;i<4;i++){
    float al = a2 ? a2[g*4+i] : 1.0f;
    float be = b2 ? b2[g*4+i] : 0.0f;
    float sw = msw[o*4+i];
    cw[i] = sw*al; cb += sw*be;
  }
  #pragma unroll
  for(int k=0;k<2;k++){
    int idx = t + 1024*k;
    Hcl[idx] = Hcin[(size_t)(g*4 + (idx>>9))*512 + (idx&511)];
  }
  __syncthreads();
  // mixc: S = sum_i w.Hc for this output o only
  if(t<512){
    int j = t, r = j>>4, c = j&15;
    float ar=0.f, ai=0.f;
    for(int i2=0;i2<4;i2++){
      float2 h = Hcl[i2*512 + j];
      float wr = wr0[((i2*4+o)*32+r)*16+c], wi = wi0[((i2*4+o)*32+r)*16+c];
      ar += wr*h.x - wi*h.y; ai += wr*h.y + wi*h.x;
    }
    Sl[j] = make_float2(ar, ai);
  }
  __syncthreads();
  float vs=0.f, dummy=0.f;
  if(t<512){
    int c = t&15;
    if(c>=1) vs = 2.0f*(Sl[t].x*Sl[t].x + Sl[t].y*Sl[t].y);
  }
  if(t<32){
    int ky = (t<16)? (t+1) : (96+t);
    float ar=0.f, ai=0.f;
    if(ky<16){ ar=Sl[ky*16].x; ai=Sl[ky*16].y; }
    else if(ky>=112){ int r=ky-96; ar=Sl[r*16].x; ai=Sl[r*16].y; }
    int kyp = 128-ky;
    float br2=0.f, bi2=0.f;
    if(kyp<16){ br2=Sl[kyp*16].x; bi2=Sl[kyp*16].y; }
    else if(kyp>=112){ int r=kyp-96; br2=Sl[r*16].x; bi2=Sl[r*16].y; }
    float pr = 0.5f*(ar+br2), pi = 0.5f*(ai-bi2);
    vs += pr*pr + pi*pi;
  }
  blockReduce2(vs, dummy, red);
  float rs2 = rsqrtf(vs + 1e-5f);
  if(t<512){
    float2 s = Sl[t];
    Sl[t] = (t==0)? make_float2(0.f,0.f) : make_float2(s.x*rs2, s.y*rs2);
  }
  __syncthreads();
  #pragma unroll
  for(int k=0;k<2;k++){
    int idx = t + 1024*k;
    int mm = idx>>4, c = idx&15;
    float vr=0.f, vi=0.f;
    for(int r=0;r<32;r++){
      int ky = (r<16)? r : 96+r;
      float2 bc = Sl[r*16+c];
      float2 cs = CS[128 + ((ky*mm)&127)];
      vr += bc.x*cs.x - bc.y*cs.y;
      vi += bc.x*cs.y + bc.y*cs.x;
    }
    float w = (c==0)?1.0f:2.0f;
    V[mm*17+c] = make_float2(vr*w, vi*w);
  }
  __syncthreads();
  {
    const int n = t&127, mm0 = t>>7;
    float2 csr[16];
    #pragma unroll
    for(int c=0;c<16;c++) csr[c] = CS[c*128+n];
    for(int k=0;k<16;k++){
      int mm = mm0 + 8*k;
      float cv = 0.f;
      #pragma unroll
      for(int c=0;c<16;c++){
        float2 v2 = V[mm*17+c];
        cv += v2.x*csr[c].x - v2.y*csr[c].y;
      }
      V2p[mm*132+n] = cv;
    }
  }
  __syncthreads();
  const float4* in4 = (const float4*)(inmaps + (size_t)(g*4)*16384);
  float4* V24 = (float4*)V2p;
  float4* o4 = (float4*)(outp + (size_t)mmap*16384);
  float s1=0.f, s2=0.f;
  for(int k=0;k<4;k++){
    int q = t + 1024*k;
    int row = q>>5, c4 = q&31;
    float4 v0 = in4[q], v1 = in4[4096+q], v2 = in4[8192+q], v3 = in4[12288+q];
    float4 cc = V24[row*33+c4];
    float4 ov;
    ov.x = cb + cw[0]*v0.x + cw[1]*v1.x + cw[2]*v2.x + cw[3]*v3.x + cc.x;
    ov.y = cb + cw[0]*v0.y + cw[1]*v1.y + cw[2]*v2.y + cw[3]*v3.y + cc.y;
    ov.z = cb + cw[0]*v0.z + cw[1]*v1.z + cw[2]*v2.z + cw[3]*v3.z + cc.z;
    ov.w = cb + cw[0]*v0.w + cw[1]*v1.w + cw[2]*v2.w + cw[3]*v3.w + cc.w;
    if(dogelu){
      ov.x = 0.5f*ov.x*(1.0f+erff(ov.x*0.70710678118f));
      ov.y = 0.5f*ov.y*(1.0f+erff(ov.y*0.70710678118f));
      ov.z = 0.5f*ov.z*(1.0f+erff(ov.z*0.70710678118f));
      ov.w = 0.5f*ov.w*(1.0f+erff(ov.w*0.70710678118f));
    }
    if(addsrc){
      s1 += ov.x+ov.y+ov.z+ov.w;
      s2 += ov.x*ov.x+ov.y*ov.y+ov.z*ov.z+ov.w*ov.w;
      V24[row*33+c4] = ov;
    } else {
      o4[q] = ov;
      if(HcOut) V24[row*33+c4] = ov;
    }
  }
  if(addsrc){
    blockReduce2(s1,s2,red);
    float mu = s1*(1.0f/16384.0f);
    float var = s2*(1.0f/16384.0f)-mu*mu;
    float rs = rsqrtf(var+1e-5f);
    float w = mw[o], b = mbv[o];
    const float4* a4 = (const float4*)(addsrc + (size_t)mmap*16384);
    for(int k=0;k<4;k++){
      int q = t + 1024*k;
      int row = q>>5, c4 = q&31;
      float4 v = V24[row*33+c4], av = a4[q];
      float4 ov;
      ov.x = (v.x-mu)*rs*w + b + av.x;
      ov.y = (v.y-mu)*rs*w + b + av.y;
      ov.z = (v.z-mu)*rs*w + b + av.z;
      ov.w = (v.w-mu)*rs*w + b + av.w;
      o4[q] = ov;
    }
  }
  if(HcOut){
    __syncthreads();
    {  // stage 1
      const int yl = t&31, c = (t>>5)&15, half = t>>9;
      for(int yc=2*half; yc<2*half+2; yc++){
        int y = yc*32+yl;
        float ar=0.f, ai=0.f;
        for(int n=0;n<128;n++){
          float zv = V2p[y*132+n];
          float2 cs = CS[c*128+n];
          ar += zv*cs.x; ai -= zv*cs.y;
        }
        V[y*17+c] = make_float2(ar, ai);
      }
    }
    __syncthreads();
    if(t<512){  // stage 2
      int idx = t;
      int r = idx>>4, c = idx&15;
      int ky = (r<16)? r : 96+r;
      float hr=0.f, hi=0.f;
      for(int y=0;y<128;y++){
        float2 Rv = V[y*17+c];
        float2 cs = CS[128 + ((ky*y)&127)];
        hr += Rv.x*cs.x + Rv.y*cs.y;
        hi += Rv.y*cs.x - Rv.x*cs.y;
      }
      HcOut[mmap*512+idx] = make_float2(hr*(1.0f/16384.0f), hi*(1.0f/16384.0f));
    }
  }
}

extern "C" void kernel_launch(void* const* d_in, const int* in_sizes, int n_in,
                              void* d_out, int out_size, void* d_ws, size_t ws_size,
                              hipStream_t stream)
{
  const float* x        = (const float*)d_in[0];
  const float* norm1_w  = (const float*)d_in[1];
  const float* norm1_b  = (const float*)d_in[2];
  const float* kqv_wr   = (const float*)d_in[3];
  const float* kqv_wi   = (const float*)d_in[4];
  const float* kqv_bias = (const float*)d_in[5];
  const float* kqv_sw   = (const float*)d_in[6];
  const float* kqv_sb   = (const float*)d_in[7];
  const float* p_wr     = (const float*)d_in[8];
  const float* p_wi     = (const float*)d_in[9];
  const float* p_bias   = (const float*)d_in[10];
  const float* p_sw     = (const float*)d_in[11];
  const float* p_sb     = (const float*)d_in[12];
  const float* attn_norm_w = (const float*)d_in[13];
  const float* attn_norm_b = (const float*)d_in[14];
  const float* norm2_w  = (const float*)d_in[15];
  const float* norm2_b  = (const float*)d_in[16];
  const float* mix_wr   = (const float*)d_in[17];
  const float* mix_wi   = (const float*)d_in[18];
  // mix_bias (d_in[19]) only shifts the spectral mean which IN removes -> unused
  const float* mix_sw   = (const float*)d_in[20];
  const float* mix_sb   = (const float*)d_in[21];
  const float* mon_w    = (const float*)d_in[22];
  const float* mon_b    = (const float*)d_in[23];
  float* out = (float*)d_out;

  const size_t NEED = (size_t)26576128 * sizeof(float);
  if(ws_size < NEED) return;

  float* ws = (float*)d_ws;
  size_t off = 0;
  float2* CS  = (float2*)(ws + off); off += 32768;
  float* a1   = ws + off; off += 256;
  float* b1   = ws + off; off += 256;
  float* a2   = ws + off; off += 256;
  float* b2   = ws + off; off += 256;
  float* pbeta= ws + off; off += 256;
  float2* Xt2 = (float2*)(ws + off); off += 1081344;
  float* pool = ws + off; off += 17301504;
  float* P    = ws + off; off += 262144;
  float* PAT  = ws + off; off += 32768;
  float2* Xp  = (float2*)(ws + off); off += 262144;
  float* Zc_unused = ws + off; off += 2097152;
  float2* Bc  = (float2*)(ws + off); off += 262144;
  float* attn = ws + off; off += 4194304;
  float2* Hc  = (float2*)(ws + off); off += 524288;
  float2* Hc2 = (float2*)(ws + off); off += 524288;   // was Sn
  (void)Zc_unused;

  float* Pp   = attn;                  // 16 x 262144 partials, dead before epi0

  // pool slots
  float2* Kc = (float2*)pool;                      // 8650752 floats (4325376 cplx)
  float* R1r = pool + 8650752;         // dead after k_p2 (disjoint from Kc)
  float* R1i = pool + 8650752 + 1081344;
  float* y0g = pool;                   // after softmax (Kc dead)
  float* h1  = pool + 4325376;

  k_tables<<<dim3(128), dim3(128), 0, stream>>>(CS);
  k_instats<<<dim3(256), dim3(256), 0, stream>>>(x, norm1_w, norm1_b, a1, b1);
  k_p1<<<dim3(1024), dim3(256), 0, stream>>>(x, R1r, R1i, CS);
  k_p2<<<dim3(256), dim3(704), 0, stream>>>(R1r, R1i, CS, a1, norm1_b, Xt2, Xp);
  k_build_k<<<dim3(2048), dim3(256), 0, stream>>>(Xt2, kqv_wr, kqv_wi, kqv_bias,
                                                  kqv_sw, kqv_sb, Kc);
  k_scores<<<dim3(1024), dim3(256), 0, stream>>>(Xt2, Kc, Pp);
  k_softmax<<<dim3(2048), dim3(64), 0, stream>>>(Pp, P);
  k_peff<<<dim3(128), dim3(256), 0, stream>>>(P, p_sw, kqv_sw, a1, PAT);
  k_pbeta<<<dim3(256), dim3(128), 0, stream>>>(P, p_sw, kqv_sw, b1, pbeta);
  k_zcorr<<<dim3(256), dim3(512), 0, stream>>>(P, Xp, kqv_wr, kqv_wi, kqv_bias, kqv_sw, kqv_sb,
                                               p_wr, p_wi, p_bias, p_sw, p_sb, Bc);
  k_attn_gemm<<<dim3(512), dim3(256), 0, stream>>>(PAT, x, pbeta, y0g);
  k_epi0<<<dim3(256), dim3(1024), 0, stream>>>(y0g, x, Bc, CS, attn_norm_w, attn_norm_b,
                                               norm2_w, norm2_b, attn, a2, b2, Hc);
  // mixer layer 1 (fused mixc; emits h1 + Hc2(h1))
  k_mixinv<<<dim3(256), dim3(1024), 0, stream>>>(Hc, attn, a2, b2, mix_wr, mix_wi,
                                                 mix_sw, mix_sb, CS, 1,
                                                 Hc2, (const float*)nullptr,
                                                 (const float*)nullptr, (const float*)nullptr, h1);
  // mixer layer 2 (fused mixc; absorbs epi2: final IN + attn add -> out)
  k_mixinv<<<dim3(256), dim3(1024), 0, stream>>>(Hc2, h1, (const float*)nullptr, (const float*)nullptr,
                                                 mix_wr+8192, mix_wi+8192, mix_sw+16, mix_sb+4, CS, 0,
                                                 (float2*)nullptr, attn, mon_w, mon_b, out);
}

// Round 15
// 339.033 us; speedup vs baseline: 1.3115x; 1.1095x over previous
//
#include <hip/hip_runtime.h>
#include <math.h>

// TNO block, round 15: score factorization S = sc_h*G + D.
//  - G[b,t,s] = <X_t, wsc*Pi X_s>  (head-independent Gram, 32 f-partials)
//  - D[b,h,t,s] = <X_t|sup, Delta_{s,h}>, Delta supported on 129 corner modes
//  - replaces build_k (35MB Kc) + 2.2GFLOP scores with ~0.4 GFLOP total
// Spectra: forward-normalized, x[y][n] = sum A e^{+2pi i(ky y+kx n)/128}.

#define NT 2112   // 64*33 truncated spectrum per map
#define NSUP 132  // 129 support modes + 3 pad

__device__ __forceinline__ void blockReduce2(float& a, float& b, float* red){
  const int tid = threadIdx.x, n = blockDim.x;
  red[tid] = a; red[n+tid] = b;
  __syncthreads();
  for(int off=n>>1; off>0; off>>=1){
    if(tid<off){ red[tid]+=red[tid+off]; red[n+tid]+=red[n+tid+off]; }
    __syncthreads();
  }
  a = red[0]; b = red[n];
  __syncthreads();
}

__device__ __forceinline__ float2 cmul_add(float2 acc, float2 w, float2 x){
  acc.x += w.x*x.x - w.y*x.y;
  acc.y += w.x*x.y + w.y*x.x;
  return acc;
}

// support slot u -> (r,c):  u<112: c=1+(u>>4), k=u&15, r=k<8?k:48+k
//                           u>=112: c=0, v=u-112, r=v<9?v:47+v
__device__ __forceinline__ void sup_rc(int u, int& r, int& c){
  if(u<112){ c = (u>>4)+1; int k = u&15; r = (k<8)? k : 48+k; }
  else { int v = u-112; c = 0; r = (v<9)? v : 47+v; }
}

// ---------------- twiddle table ----------------
__global__ void k_tables(float2* __restrict__ CS){
  int a = blockIdx.x, b = threadIdx.x;
  int p = (a*b)&127;
  float t = (float)p * (1.0f/64.0f);
  CS[a*128+b] = make_float2(cospif(t), sinpif(t));
}

// ---------------- per-map IN stats of x ----------------
__global__ __launch_bounds__(256) void k_instats(
    const float* __restrict__ xin, const float* __restrict__ n1w,
    const float* __restrict__ n1b, float* __restrict__ a1, float* __restrict__ b1)
{
  __shared__ float red[512];
  const int m = blockIdx.x, t = threadIdx.x;
  const float* xp = xin + (size_t)m*16384;
  float s1=0.f, s2=0.f;
  for(int i=t;i<4096;i+=256){
    float4 v = ((const float4*)xp)[i];
    s1 += v.x+v.y+v.z+v.w;
    s2 += v.x*v.x+v.y*v.y+v.z*v.z+v.w*v.w;
  }
  blockReduce2(s1,s2,red);
  if(t==0){
    float mu = s1*(1.0f/16384.0f);
    float var = s2*(1.0f/16384.0f)-mu*mu;
    float a = n1w[0]*rsqrtf(var+1e-5f);
    a1[m] = a; b1[m] = n1b[0] - mu*a;
  }
}

// ---------------- k_p1: x-dim partial DFT ----------------
__global__ __launch_bounds__(256) void k_p1(
    const float* __restrict__ xin, float* __restrict__ R1r, float* __restrict__ R1i,
    const float2* __restrict__ CS)
{
  __shared__ float xl[32*129];
  __shared__ float2 csl[4224];
  const int bid = blockIdx.x;
  const int m = bid>>2, yt = bid&3;
  const int t = threadIdx.x;
  for(int i=t;i<4224;i+=256) csl[i] = CS[i];
  {
    const float4* xp4 = (const float4*)(xin + (size_t)m*16384 + yt*4096);
    for(int i4=t;i4<1024;i4+=256){
      float4 v = xp4[i4];
      int y = i4>>5, n = (i4&31)*4;
      xl[y*129+n]=v.x; xl[y*129+n+1]=v.y; xl[y*129+n+2]=v.z; xl[y*129+n+3]=v.w;
    }
  }
  __syncthreads();
  const int yl = t&31, cg = t>>5;
  const int nc = (cg==0)?5:4;
  float ar[5]={0,0,0,0,0}, ai[5]={0,0,0,0,0};
  for(int n=0;n<128;n++){
    float xv = xl[yl*129+n];
    #pragma unroll
    for(int k=0;k<5;k++){
      if(k<nc){
        float2 cs = csl[(cg+8*k)*128+n];
        ar[k] += xv*cs.x;
        ai[k] -= xv*cs.y;
      }
    }
  }
  __syncthreads();
  #pragma unroll
  for(int k=0;k<5;k++){
    if(k<nc){
      int c = cg+8*k;
      xl[yl*33+c] = ar[k];
      xl[1056 + yl*33+c] = ai[k];
    }
  }
  __syncthreads();
  const int gb = m*4224 + yt*1056;
  for(int idx=t; idx<2112; idx+=256){
    if(idx<1056) R1r[gb+idx] = xl[idx];
    else         R1i[gb+idx-1056] = xl[idx];
  }
}

// ---------------- k_p2: y-dim DFT -> Xt2 (+ Xp gather) ----------------
__global__ __launch_bounds__(704) void k_p2(
    const float* __restrict__ R1r, const float* __restrict__ R1i,
    const float2* __restrict__ CS, const float* __restrict__ a1,
    const float* __restrict__ n1b,
    float2* __restrict__ Xt2, float2* __restrict__ Xp)
{
  __shared__ float2 Rl[128*34];
  const int m = blockIdx.x, t = threadIdx.x;
  for(int idx=t; idx<4224; idx+=704){
    int y = idx/33, c = idx - y*33;
    Rl[y*34+c] = make_float2(R1r[m*4224+idx], R1i[m*4224+idx]);
  }
  __syncthreads();
  const float sc = a1[m]*(1.0f/16384.0f);
  const int r = t&63;
  const int ky = (r<32)? r : r+64;
  #pragma unroll
  for(int k=0;k<3;k++){
    int c = (t>>6) + 11*k;
    float ar=0.f, ai=0.f;
    for(int y=0;y<128;y++){
      float2 Rv = Rl[y*34+c];
      float2 cs = CS[128 + ((ky*y)&127)];
      ar += Rv.x*cs.x + Rv.y*cs.y;
      ai += Rv.y*cs.x - Rv.x*cs.y;
    }
    int j = r*33 + c;
    float vr = ar*sc, vi = ai*sc;
    if(j==0){ vr = n1b[0]; vi = 0.f; }
    Xt2[m*NT+j] = make_float2(vr, vi);
    if(c<16 && (r<16 || r>=48)){
      int rp = (r<16)? r : r-32;
      Xp[m*512 + rp*16 + c] = make_float2(vr, vi);
    }
  }
}

// ---------------- k_build_w: Xw = wsc * Pi(X) ----------------
__global__ __launch_bounds__(256) void k_build_w(
  const float2* __restrict__ Xt2, float2* __restrict__ Xw)
{
  __shared__ float2 T[2112];
  const int m = blockIdx.x, t = threadIdx.x;
  for(int j=t;j<2112;j+=256) T[j] = Xt2[m*NT+j];
  __syncthreads();
  for(int j=t;j<2112;j+=256){
    int r = j/33, c = j - r*33;
    float2 X = T[j];
    float wsc = 128.0f;
    if(c==0 || c==32){
      int pj = ((64-r)&63)*33 + c;
      float2 X2 = T[pj];
      X = make_float2(0.5f*(X.x+X2.x), 0.5f*(X.y-X2.y));
      wsc = 64.0f;
    }
    Xw[m*NT+j] = make_float2(X.x*wsc, X.y*wsc);
  }
}

// ---------------- k_build_d: Delta_{m,h}[u] = K''[u] - sc*wsc*PiX[u] -----------
__global__ __launch_bounds__(256) void k_build_d(
  const float2* __restrict__ Xt2,
  const float* __restrict__ kqv_wr, const float* __restrict__ kqv_wi,
  const float* __restrict__ kqv_bias, const float* __restrict__ kqv_sw,
  const float* __restrict__ kqv_sb,
  float2* __restrict__ DL)
{
  const int bid = blockIdx.x;
  const int m = bid & 255, h = bid >> 8;
  const int u = threadIdx.x;
  if(u >= NSUP) return;
  float2 dv = make_float2(0.f, 0.f);
  if(u < 129){
    const float swK = kqv_sw[h], swQ = kqv_sw[8+h];
    const float biasK = kqv_bias[h] + kqv_sb[h];
    int r, c; sup_rc(u, r, c);
    float2 X = Xt2[m*NT + r*33 + c];
    float2 K1 = make_float2(swK*X.x, swK*X.y);
    int wr_ = (r<8)? r : ((r>=56)? r-48 : -1);
    if(wr_>=0)
      K1 = cmul_add(K1, make_float2(kqv_wr[(h*16+wr_)*8+c], kqv_wi[(h*16+wr_)*8+c]), X);
    if(r==0 && c==0) K1.x += biasK;
    float2 PK, PX;
    if(c==0){
      int rp = (64-r)&63;
      float2 Xp_ = Xt2[m*NT + rp*33];
      float2 K1p = make_float2(swK*Xp_.x, swK*Xp_.y);
      int wrp = (rp<8)? rp : ((rp>=56)? rp-48 : -1);
      if(wrp>=0)
        K1p = cmul_add(K1p, make_float2(kqv_wr[(h*16+wrp)*8], kqv_wi[(h*16+wrp)*8]), Xp_);
      if(rp==0) K1p.x += biasK;
      PK = make_float2(0.5f*(K1.x+K1p.x), 0.5f*(K1.y-K1p.y));
      PX = make_float2(0.5f*(X.x+Xp_.x), 0.5f*(X.y-Xp_.y));
    } else { PK = K1; PX = X; }
    float ar = swQ, ai = 0.f;
    if(wr_>=0){ ar += kqv_wr[((8+h)*16+wr_)*8+c]; ai += kqv_wi[((8+h)*16+wr_)*8+c]; }
    float wsc = (c==0)? 64.0f : 128.0f;
    float2 Kpp = make_float2(wsc*(ar*PK.x + ai*PK.y), wsc*(ar*PK.y - ai*PK.x));
    float scq = swQ*swK*wsc;
    dv = make_float2(Kpp.x - scq*PX.x, Kpp.y - scq*PX.y);
  }
  DL[(size_t)(m*8+h)*NSUP + u] = dv;
}

// ---------------- k_scoresG: G partials, 64x64 tiles, 32 f-splits --------------
__global__ __launch_bounds__(256) void k_scoresG(
  const float2* __restrict__ Xt2, const float2* __restrict__ Xw,
  float* __restrict__ Gp)
{
  __shared__ float Qs[64*52];
  __shared__ float Ks[64*52];
  const int bid = blockIdx.x;
  const int fq = bid&31, st = (bid>>5)&1, tt = (bid>>6)&1, b = bid>>7;
  const int t = threadIdx.x;
  const int tg = t>>4, sg = t&15;
  const int t0 = tt*64, s0 = st*64;
  const int fb = fq*66;
  float acc[4][4];
  #pragma unroll
  for(int i=0;i<4;i++)
    #pragma unroll
    for(int j=0;j<4;j++) acc[i][j]=0.f;
  for(int sub=0; sub<3; sub++){
    __syncthreads();
    const int fo = fb + sub*22;
    for(int idx=t; idx<1408; idx+=256){
      int rl = idx/22, f2 = idx - rl*22;
      float2 q = Xt2[(size_t)(b*128 + t0+rl)*NT + fo + f2];
      ((float2*)(Qs + rl*52))[f2] = q;
      float2 kk = Xw[(size_t)(b*128 + s0+rl)*NT + fo + f2];
      ((float2*)(Ks + rl*52))[f2] = kk;
    }
    __syncthreads();
    #pragma unroll
    for(int f4=0; f4<11; f4++){
      float4 qv[4], kv[4];
      #pragma unroll
      for(int i=0;i<4;i++) qv[i] = *(const float4*)&Qs[(tg+16*i)*52 + f4*4];
      #pragma unroll
      for(int j=0;j<4;j++) kv[j] = *(const float4*)&Ks[(sg+16*j)*52 + f4*4];
      #pragma unroll
      for(int i=0;i<4;i++)
        #pragma unroll
        for(int j=0;j<4;j++)
          acc[i][j] += qv[i].x*kv[j].x + qv[i].y*kv[j].y
                     + qv[i].z*kv[j].z + qv[i].w*kv[j].w;
    }
  }
  #pragma unroll
  for(int i=0;i<4;i++){
    int tg2 = t0 + tg + 16*i;
    #pragma unroll
    for(int j=0;j<4;j++){
      int s = s0 + sg + 16*j;
      Gp[(size_t)(fq*2+b)*16384 + tg2*128 + s] = acc[i][j];
    }
  }
}

// ---------------- k_scoresD: D[b,h,t,s] over 129 support modes -----------------
__global__ __launch_bounds__(256) void k_scoresD(
  const float2* __restrict__ Xt2, const float2* __restrict__ DL,
  float* __restrict__ Dout)
{
  __shared__ float XT[32*268];
  __shared__ float DS[32*268];
  const int bid = blockIdx.x;
  const int b = bid>>7, h = (bid>>4)&7, tt4 = (bid>>2)&3, st4 = bid&3;
  const int t0 = tt4*32, s0 = st4*32;
  const int t = threadIdx.x;
  for(int idx=t; idx<32*NSUP; idx+=256){
    int row = idx/NSUP, u = idx - row*NSUP;
    float2 v = make_float2(0.f,0.f);
    if(u<129){
      int r, c; sup_rc(u, r, c);
      v = Xt2[(size_t)(b*128 + t0+row)*NT + r*33 + c];
    }
    XT[row*268 + 2*u] = v.x; XT[row*268 + 2*u+1] = v.y;
    float2 d = DL[(size_t)((b*128 + s0+row)*8 + h)*NSUP + u];
    DS[row*268 + 2*u] = d.x; DS[row*268 + 2*u+1] = d.y;
  }
  __syncthreads();
  const int tq = t>>4, sq = t&15;
  float acc[2][2] = {{0.f,0.f},{0.f,0.f}};
  for(int f4=0; f4<66; f4++){
    float4 xa0 = *(const float4*)&XT[(tq*2+0)*268 + f4*4];
    float4 xa1 = *(const float4*)&XT[(tq*2+1)*268 + f4*4];
    float4 da0 = *(const float4*)&DS[(sq*2+0)*268 + f4*4];
    float4 da1 = *(const float4*)&DS[(sq*2+1)*268 + f4*4];
    acc[0][0] += xa0.x*da0.x + xa0.y*da0.y + xa0.z*da0.z + xa0.w*da0.w;
    acc[0][1] += xa0.x*da1.x + xa0.y*da1.y + xa0.z*da1.z + xa0.w*da1.w;
    acc[1][0] += xa1.x*da0.x + xa1.y*da0.y + xa1.z*da0.z + xa1.w*da0.w;
    acc[1][1] += xa1.x*da1.x + xa1.y*da1.y + xa1.z*da1.z + xa1.w*da1.w;
  }
  #pragma unroll
  for(int i=0;i<2;i++)
    #pragma unroll
    for(int j=0;j<2;j++)
      Dout[(size_t)((b*8+h)*128 + t0+tq*2+i)*128 + s0+sq*2+j] = acc[i][j];
}

// ---------------- softmax: S = sc_h*sum(Gp) + D -> P ---------------------------
__global__ __launch_bounds__(64) void k_softmax(const float* __restrict__ Gp,
                                                const float* __restrict__ Dout,
                                                const float* __restrict__ kqv_sw,
                                                float* __restrict__ P){
  const int row = blockIdx.x, tid = threadIdx.x;
  const int b = row>>10, h = (row>>7)&7, trow = row&127;
  const float sch = kqv_sw[8+h]*kqv_sw[h];
  const size_t gbase = (size_t)b*16384 + trow*128;
  float v0=0.f, v1=0.f;
  #pragma unroll
  for(int q=0;q<32;q++){
    v0 += Gp[(size_t)(q*2)*16384 + gbase + tid];
    v1 += Gp[(size_t)(q*2)*16384 + gbase + tid + 64];
  }
  size_t o = (size_t)row*128;
  v0 = sch*v0 + Dout[o+tid];
  v1 = sch*v1 + Dout[o+tid+64];
  float mx = fmaxf(v0,v1);
  for(int off=32; off; off>>=1) mx = fmaxf(mx, __shfl_xor(mx, off));
  float e0 = expf(v0-mx), e1 = expf(v1-mx);
  float s = e0+e1;
  for(int off=32; off; off>>=1) s += __shfl_xor(s, off);
  float inv = 1.0f/s;
  P[o+tid] = e0*inv; P[o+tid+64] = e1*inv;
}

// PA^T[b][s][t] = alpha1[b*128+s] * sum_h psw*sv*P[b,h,t,s]
__global__ __launch_bounds__(256) void k_peff(const float* __restrict__ P,
   const float* __restrict__ p_sw, const float* __restrict__ kqv_sw,
   const float* __restrict__ a1, float* __restrict__ PAT)
{
  const int i = blockIdx.x*256 + threadIdx.x;
  const int b = i>>14, rem = i&16383;
  const int tch = rem>>7, s = rem&127;
  float acc=0.f;
  for(int hh=0; hh<8; hh++){
    float a = p_sw[hh]*kqv_sw[16+hh];
    acc += a * P[(((size_t)(b*8+hh))<<14) + rem];
  }
  PAT[((size_t)(b*128+s))*128 + tch] = acc * a1[b*128+s];
}

// pbeta[b*128+t] = sum_s (sum_h psw*sv*P) * beta1[b*128+s]
__global__ __launch_bounds__(128) void k_pbeta(const float* __restrict__ P,
   const float* __restrict__ p_sw, const float* __restrict__ kqv_sw,
   const float* __restrict__ b1, float* __restrict__ pbeta)
{
  __shared__ float red[128];
  const int bid = blockIdx.x;
  const int b = bid>>7, tch = bid&127;
  const int s = threadIdx.x;
  float acc=0.f;
  for(int hh=0; hh<8; hh++){
    float a = p_sw[hh]*kqv_sw[16+hh];
    acc += a * P[((size_t)((b*8+hh)*128+tch))*128 + s];
  }
  acc *= b1[b*128+s];
  red[s] = acc; __syncthreads();
  for(int off=64; off>0; off>>=1){
    if(s<off) red[s]+=red[s+off];
    __syncthreads();
  }
  if(s==0) pbeta[bid] = red[0];
}

// ---------------- k_zcorr: Z (per map, all heads, 512 modes) + corr ------------
__global__ __launch_bounds__(512) void k_zcorr(
  const float* __restrict__ P, const float2* __restrict__ Xp,
  const float* __restrict__ kqv_wr, const float* __restrict__ kqv_wi,
  const float* __restrict__ kqv_bias, const float* __restrict__ kqv_sw, const float* __restrict__ kqv_sb,
  const float* __restrict__ p_wr, const float* __restrict__ p_wi,
  const float* __restrict__ p_bias, const float* __restrict__ p_sw, const float* __restrict__ p_sb,
  float2* __restrict__ Bc)
{
  __shared__ float4 Xs4[4096];
  __shared__ float Pl[1024];
  const int m = blockIdx.x;
  const int b = m>>7, cix = m&127;
  const int t = threadIdx.x;
  const int j = t;
  for(int idx=t; idx<1024; idx+=512){
    int o = idx>>7, s = idx&127;
    Pl[idx] = P[((size_t)((b*8+o)*128 + cix))*128 + s];
  }
  float2 z[8];
  #pragma unroll
  for(int o=0;o<8;o++) z[o] = make_float2(0.f,0.f);
  const float2* Xs = (const float2*)Xs4;
  for(int st=0; st<8; st++){
    __syncthreads();
    for(int q=t; q<4096; q+=512){
      int sl = q>>8, f4 = q&255;
      Xs4[q] = ((const float4*)(Xp + (size_t)(b*128 + st*16 + sl)*512))[f4];
    }
    __syncthreads();
    for(int sl=0; sl<16; sl++){
      int s = st*16 + sl;
      float2 xv = Xs[sl*512 + j];
      #pragma unroll
      for(int o=0;o<8;o++){
        float p = Pl[o*128+s];
        z[o].x += p*xv.x; z[o].y += p*xv.y;
      }
    }
  }
  __syncthreads();
  float2* Zl = (float2*)Xs4;
  #pragma unroll
  for(int o=0;o<8;o++) Zl[o*512 + j] = z[o];
  __syncthreads();
  {
    int r = j>>4, c = j&15;
    int ky = (r<16)? r : 96+r;
    float accr=0.f, acci=0.f;
    int rp = -1;
    if(c==0){ int kyp = (128-ky)&127; rp = (kyp<16)? kyp : ((kyp>=112)? kyp-96 : -1); }
    for(int o=0;o<8;o++){
      float2 zv = Zl[o*512 + j];
      float cvr=0.f, cvi=0.f;
      bool inV = (c<8) && (ky<8 || ky>=120);
      if(inV){
        int vrow = (ky<8)? ky : 8+(ky-120);
        float wr = kqv_wr[((16+o)*16+vrow)*8+c], wi = kqv_wi[((16+o)*16+vrow)*8+c];
        cvr = wr*zv.x - wi*zv.y; cvi = wr*zv.y + wi*zv.x;
      }
      float ar = cvr, ai = cvi;
      if(c==0){
        float pvr=0.f, pvi=0.f;
        int kyp = (128-ky)&127;
        bool pInV = (kyp<8 || kyp>=120);
        if(pInV && rp>=0){
          int vrow = (kyp<8)? kyp : 8+(kyp-120);
          float2 z2 = Zl[o*512 + rp*16];
          float wr = kqv_wr[((16+o)*16+vrow)*8], wi = kqv_wi[((16+o)*16+vrow)*8];
          pvr = wr*z2.x - wi*z2.y; pvi = wr*z2.y + wi*z2.x;
        }
        ar = 0.5f*(cvr + pvr);
        ai = 0.5f*(cvi - pvi);
      }
      float sv = kqv_sw[16+o];
      float Dv = kqv_bias[16+o] + kqv_sb[16+o];
      float atr = sv*zv.x + ar + ((j==0)? Dv : 0.f);
      float ati = sv*zv.y + ai;
      float psw = p_sw[o];
      accr += psw*ar;  acci += psw*ai;
      float wpr = p_wr[(o*32+r)*16+c], wpi = p_wi[(o*32+r)*16+c];
      accr += wpr*atr - wpi*ati;
      acci += wpr*ati + wpi*atr;
      if(j==0) accr += psw*Dv;
    }
    if(j==0) accr += p_bias[0] + p_sb[0];
    Bc[m*512+j] = make_float2(accr, acci);
  }
}

// ---------------- attn GEMM ----------------
__global__ __launch_bounds__(256) void k_attn_gemm(
  const float* __restrict__ PAT, const float* __restrict__ xin,
  const float* __restrict__ pbeta, float* __restrict__ y0g)
{
  __shared__ float PAs[32*33];
  __shared__ float Xs[32*256];
  const int bid = blockIdx.x;
  const int b = bid>>8, ct = (bid>>6)&3, pt = bid&63;
  const int t = threadIdx.x;
  const int tc = t>>6, tp = t&63;
  float4 acc[8];
  #pragma unroll
  for(int k=0;k<8;k++) acc[k] = make_float4(0.f,0.f,0.f,0.f);
  for(int sc4=0; sc4<4; sc4++){
    __syncthreads();
    for(int idx=t; idx<1024; idx+=256){
      int sl = idx>>5, cl = idx&31;
      PAs[sl*33+cl] = PAT[((size_t)(b*128 + sc4*32+sl))*128 + ct*32+cl];
    }
    for(int q=t; q<2048; q+=256){
      int sl = q>>6, p4 = q&63;
      ((float4*)Xs)[q] =
        ((const float4*)xin)[((size_t)(b*128 + sc4*32+sl))*4096 + pt*64 + p4];
    }
    __syncthreads();
    for(int sl=0; sl<32; sl++){
      float4 xv = ((const float4*)Xs)[sl*64+tp];
      #pragma unroll
      for(int k=0;k<8;k++){
        float pa = PAs[sl*33 + tc*8+k];
        acc[k].x += pa*xv.x; acc[k].y += pa*xv.y;
        acc[k].z += pa*xv.z; acc[k].w += pa*xv.w;
      }
    }
  }
  #pragma unroll
  for(int k=0;k<8;k++){
    int c = ct*32 + tc*8 + k;
    float pb = pbeta[b*128+c];
    float4 o = acc[k];
    o.x += pb; o.y += pb; o.z += pb; o.w += pb;
    ((float4*)y0g)[((size_t)(b*128+c))*4096 + pt*64 + tp] = o;
  }
}

// ---------------- epi0 (1024 threads) ----------------
__global__ __launch_bounds__(1024) void k_epi0(
  const float* __restrict__ y0g, const float* __restrict__ xin,
  const float2* __restrict__ Bc,
  const float2* __restrict__ CS,
  const float* __restrict__ awp, const float* __restrict__ abp,
  const float* __restrict__ n2w, const float* __restrict__ n2b,
  float* __restrict__ attn, float* __restrict__ a2, float* __restrict__ b2,
  float2* __restrict__ Hc)
{
  __shared__ float2 Bcl[512];
  __shared__ float2 V[128*17];
  __shared__ float V2p[128*132];
  __shared__ float red[2048];
  const int m = blockIdx.x, t = threadIdx.x;
  if(t<512) Bcl[t] = Bc[m*512+t];
  __syncthreads();
  #pragma unroll
  for(int k=0;k<2;k++){
    int idx = t + 1024*k;
    int mm = idx>>4, c = idx&15;
    float vr=0.f, vi=0.f;
    for(int r=0;r<32;r++){
      int ky = (r<16)? r : 96+r;
      float2 bc = Bcl[r*16+c];
      float2 cs = CS[128 + ((ky*mm)&127)];
      vr += bc.x*cs.x - bc.y*cs.y;
      vi += bc.x*cs.y + bc.y*cs.x;
    }
    float w = (c==0)?1.0f:2.0f;
    V[mm*17+c] = make_float2(vr*w, vi*w);
  }
  __syncthreads();
  {
    const int n = t&127, mm0 = t>>7;
    float2 csr[16];
    #pragma unroll
    for(int c=0;c<16;c++) csr[c] = CS[c*128+n];
    for(int k=0;k<16;k++){
      int mm = mm0 + 8*k;
      float cv = 0.f;
      #pragma unroll
      for(int c=0;c<16;c++){
        float2 v2 = V[mm*17+c];
        cv += v2.x*csr[c].x - v2.y*csr[c].y;
      }
      V2p[mm*132+n] = cv;
    }
  }
  __syncthreads();
  const float4* x4 = (const float4*)(xin + (size_t)m*16384);
  const float4* g4 = (const float4*)(y0g + (size_t)m*16384);
  float4* V24 = (float4*)V2p;
  float s1=0.f, s2=0.f;
  for(int k=0;k<4;k++){
    int q = t + 1024*k;
    int row = q>>5, c4 = q&31;
    float4 xv = x4[q], gv = g4[q], cc = V24[row*33+c4];
    float4 v;
    v.x = xv.x+gv.x+cc.x; v.y = xv.y+gv.y+cc.y;
    v.z = xv.z+gv.z+cc.z; v.w = xv.w+gv.w+cc.w;
    s1 += v.x+v.y+v.z+v.w;
    s2 += v.x*v.x+v.y*v.y+v.z*v.z+v.w*v.w;
    V24[row*33+c4] = v;
  }
  blockReduce2(s1,s2,red);
  float mu = s1*(1.0f/16384.0f);
  float var = s2*(1.0f/16384.0f)-mu*mu;
  float rs = rsqrtf(var+1e-5f);
  float aw = awp[0], ab = abp[0];
  float4* at4 = (float4*)(attn + (size_t)m*16384);
  for(int k=0;k<4;k++){
    int q = t + 1024*k;
    int row = q>>5, c4 = q&31;
    float4 v = V24[row*33+c4];
    float4 ov;
    ov.x = (v.x-mu)*rs*aw + ab;
    ov.y = (v.y-mu)*rs*aw + ab;
    ov.z = (v.z-mu)*rs*aw + ab;
    ov.w = (v.w-mu)*rs*aw + ab;
    at4[q] = ov;
  }
  float va = aw*aw*var/(var+1e-5f);
  float al = n2w[m&3]*rsqrtf(va+1e-5f);
  if(t==0){ a2[m] = al; b2[m] = n2b[m&3] - ab*al; }
  __syncthreads();
  {
    const int yl = t&31, c = (t>>5)&15, half = t>>9;
    for(int yc=2*half; yc<2*half+2; yc++){
      int y = yc*32+yl;
      float ar=0.f, ai=0.f;
      for(int n=0;n<128;n++){
        float zv = V2p[y*132+n];
        float2 cs = CS[c*128+n];
        ar += zv*cs.x; ai -= zv*cs.y;
      }
      V[y*17+c] = make_float2(ar, ai);
    }
  }
  __syncthreads();
  if(t<512){
    const float scl = al*rs*aw*(1.0f/16384.0f);
    int idx = t;
    int r = idx>>4, c = idx&15;
    int ky = (r<16)? r : 96+r;
    float hr=0.f, hi=0.f;
    for(int y=0;y<128;y++){
      float2 Rv = V[y*17+c];
      float2 cs = CS[128 + ((ky*y)&127)];
      hr += Rv.x*cs.x + Rv.y*cs.y;
      hi += Rv.y*cs.x - Rv.x*cs.y;
    }
    float2 o = make_float2(hr*scl, hi*scl);
    if(idx==0) o = make_float2(n2b[m&3], 0.f);
    Hc[m*512+idx] = o;
  }
}

// ---------------- mixer (1024 threads): fused mixc + inverse + opt Hc/final ----
__global__ __launch_bounds__(1024) void k_mixinv(
  const float2* __restrict__ Hcin, const float* __restrict__ inmaps,
  const float* __restrict__ a2, const float* __restrict__ b2,
  const float* __restrict__ wr0, const float* __restrict__ wi0,
  const float* __restrict__ msw, const float* __restrict__ msb,
  const float2* __restrict__ CS, const int dogelu,
  float2* __restrict__ HcOut,
  const float* __restrict__ addsrc, const float* __restrict__ mw,
  const float* __restrict__ mbv,
  float* __restrict__ outp)
{
  __shared__ float2 Hcl[2048];
  __shared__ float2 Sl[512];
  __shared__ float2 V[128*17];
  __shared__ float V2p[128*132];
  __shared__ float red[2048];
  const int mb = blockIdx.x;
  const int g = mb&63, o = mb>>6;
  const int mmap = g*4+o;
  const int t = threadIdx.x;
  float cw[4]; float cb = msb[o];
  #pragma unroll
  for(int i=0;i<4;i++){
    float al = a2 ? a2[g*4+i] : 1.0f;
    float be = b2 ? b2[g*4+i] : 0.0f;
    float sw = msw[o*4+i];
    cw[i] = sw*al; cb += sw*be;
  }
  #pragma unroll
  for(int k=0;k<2;k++){
    int idx = t + 1024*k;
    Hcl[idx] = Hcin[(size_t)(g*4 + (idx>>9))*512 + (idx&511)];
  }
  __syncthreads();
  if(t<512){
    int j = t, r = j>>4, c = j&15;
    float ar=0.f, ai=0.f;
    for(int i2=0;i2<4;i2++){
      float2 h = Hcl[i2*512 + j];
      float wr = wr0[((i2*4+o)*32+r)*16+c], wi = wi0[((i2*4+o)*32+r)*16+c];
      ar += wr*h.x - wi*h.y; ai += wr*h.y + wi*h.x;
    }
    Sl[j] = make_float2(ar, ai);
  }
  __syncthreads();
  float vs=0.f, dummy=0.f;
  if(t<512){
    int c = t&15;
    if(c>=1) vs = 2.0f*(Sl[t].x*Sl[t].x + Sl[t].y*Sl[t].y);
  }
  if(t<32){
    int ky = (t<16)? (t+1) : (96+t);
    float ar=0.f, ai=0.f;
    if(ky<16){ ar=Sl[ky*16].x; ai=Sl[ky*16].y; }
    else if(ky>=112){ int r=ky-96; ar=Sl[r*16].x; ai=Sl[r*16].y; }
    int kyp = 128-ky;
    float br2=0.f, bi2=0.f;
    if(kyp<16){ br2=Sl[kyp*16].x; bi2=Sl[kyp*16].y; }
    else if(kyp>=112){ int r=kyp-96; br2=Sl[r*16].x; bi2=Sl[r*16].y; }
    float pr = 0.5f*(ar+br2), pi = 0.5f*(ai-bi2);
    vs += pr*pr + pi*pi;
  }
  blockReduce2(vs, dummy, red);
  float rs2 = rsqrtf(vs + 1e-5f);
  if(t<512){
    float2 s = Sl[t];
    Sl[t] = (t==0)? make_float2(0.f,0.f) : make_float2(s.x*rs2, s.y*rs2);
  }
  __syncthreads();
  #pragma unroll
  for(int k=0;k<2;k++){
    int idx = t + 1024*k;
    int mm = idx>>4, c = idx&15;
    float vr=0.f, vi=0.f;
    for(int r=0;r<32;r++){
      int ky = (r<16)? r : 96+r;
      float2 bc = Sl[r*16+c];
      float2 cs = CS[128 + ((ky*mm)&127)];
      vr += bc.x*cs.x - bc.y*cs.y;
      vi += bc.x*cs.y + bc.y*cs.x;
    }
    float w = (c==0)?1.0f:2.0f;
    V[mm*17+c] = make_float2(vr*w, vi*w);
  }
  __syncthreads();
  {
    const int n = t&127, mm0 = t>>7;
    float2 csr[16];
    #pragma unroll
    for(int c=0;c<16;c++) csr[c] = CS[c*128+n];
    for(int k=0;k<16;k++){
      int mm = mm0 + 8*k;
      float cv = 0.f;
      #pragma unroll
      for(int c=0;c<16;c++){
        float2 v2 = V[mm*17+c];
        cv += v2.x*csr[c].x - v2.y*csr[c].y;
      }
      V2p[mm*132+n] = cv;
    }
  }
  __syncthreads();
  const float4* in4 = (const float4*)(inmaps + (size_t)(g*4)*16384);
  float4* V24 = (float4*)V2p;
  float4* o4 = (float4*)(outp + (size_t)mmap*16384);
  float s1=0.f, s2=0.f;
  for(int k=0;k<4;k++){
    int q = t + 1024*k;
    int row = q>>5, c4 = q&31;
    float4 v0 = in4[q], v1 = in4[4096+q], v2 = in4[8192+q], v3 = in4[12288+q];
    float4 cc = V24[row*33+c4];
    float4 ov;
    ov.x = cb + cw[0]*v0.x + cw[1]*v1.x + cw[2]*v2.x + cw[3]*v3.x + cc.x;
    ov.y = cb + cw[0]*v0.y + cw[1]*v1.y + cw[2]*v2.y + cw[3]*v3.y + cc.y;
    ov.z = cb + cw[0]*v0.z + cw[1]*v1.z + cw[2]*v2.z + cw[3]*v3.z + cc.z;
    ov.w = cb + cw[0]*v0.w + cw[1]*v1.w + cw[2]*v2.w + cw[3]*v3.w + cc.w;
    if(dogelu){
      ov.x = 0.5f*ov.x*(1.0f+erff(ov.x*0.70710678118f));
      ov.y = 0.5f*ov.y*(1.0f+erff(ov.y*0.70710678118f));
      ov.z = 0.5f*ov.z*(1.0f+erff(ov.z*0.70710678118f));
      ov.w = 0.5f*ov.w*(1.0f+erff(ov.w*0.70710678118f));
    }
    if(addsrc){
      s1 += ov.x+ov.y+ov.z+ov.w;
      s2 += ov.x*ov.x+ov.y*ov.y+ov.z*ov.z+ov.w*ov.w;
      V24[row*33+c4] = ov;
    } else {
      o4[q] = ov;
      if(HcOut) V24[row*33+c4] = ov;
    }
  }
  if(addsrc){
    blockReduce2(s1,s2,red);
    float mu = s1*(1.0f/16384.0f);
    float var = s2*(1.0f/16384.0f)-mu*mu;
    float rs = rsqrtf(var+1e-5f);
    float w = mw[o], b = mbv[o];
    const float4* a4 = (const float4*)(addsrc + (size_t)mmap*16384);
    for(int k=0;k<4;k++){
      int q = t + 1024*k;
      int row = q>>5, c4 = q&31;
      float4 v = V24[row*33+c4], av = a4[q];
      float4 ov;
      ov.x = (v.x-mu)*rs*w + b + av.x;
      ov.y = (v.y-mu)*rs*w + b + av.y;
      ov.z = (v.z-mu)*rs*w + b + av.z;
      ov.w = (v.w-mu)*rs*w + b + av.w;
      o4[q] = ov;
    }
  }
  if(HcOut){
    __syncthreads();
    {
      const int yl = t&31, c = (t>>5)&15, half = t>>9;
      for(int yc=2*half; yc<2*half+2; yc++){
        int y = yc*32+yl;
        float ar=0.f, ai=0.f;
        for(int n=0;n<128;n++){
          float zv = V2p[y*132+n];
          float2 cs = CS[c*128+n];
          ar += zv*cs.x; ai -= zv*cs.y;
        }
        V[y*17+c] = make_float2(ar, ai);
      }
    }
    __syncthreads();
    if(t<512){
      int idx = t;
      int r = idx>>4, c = idx&15;
      int ky = (r<16)? r : 96+r;
      float hr=0.f, hi=0.f;
      for(int y=0;y<128;y++){
        float2 Rv = V[y*17+c];
        float2 cs = CS[128 + ((ky*y)&127)];
        hr += Rv.x*cs.x + Rv.y*cs.y;
        hi += Rv.y*cs.x - Rv.x*cs.y;
      }
      HcOut[mmap*512+idx] = make_float2(hr*(1.0f/16384.0f), hi*(1.0f/16384.0f));
    }
  }
}

extern "C" void kernel_launch(void* const* d_in, const int* in_sizes, int n_in,
                              void* d_out, int out_size, void* d_ws, size_t ws_size,
                              hipStream_t stream)
{
  const float* x        = (const float*)d_in[0];
  const float* norm1_w  = (const float*)d_in[1];
  const float* norm1_b  = (const float*)d_in[2];
  const float* kqv_wr   = (const float*)d_in[3];
  const float* kqv_wi   = (const float*)d_in[4];
  const float* kqv_bias = (const float*)d_in[5];
  const float* kqv_sw   = (const float*)d_in[6];
  const float* kqv_sb   = (const float*)d_in[7];
  const float* p_wr     = (const float*)d_in[8];
  const float* p_wi     = (const float*)d_in[9];
  const float* p_bias   = (const float*)d_in[10];
  const float* p_sw     = (const float*)d_in[11];
  const float* p_sb     = (const float*)d_in[12];
  const float* attn_norm_w = (const float*)d_in[13];
  const float* attn_norm_b = (const float*)d_in[14];
  const float* norm2_w  = (const float*)d_in[15];
  const float* norm2_b  = (const float*)d_in[16];
  const float* mix_wr   = (const float*)d_in[17];
  const float* mix_wi   = (const float*)d_in[18];
  // mix_bias (d_in[19]) unused (IN removes spectral mean shift)
  const float* mix_sw   = (const float*)d_in[20];
  const float* mix_sb   = (const float*)d_in[21];
  const float* mon_w    = (const float*)d_in[22];
  const float* mon_b    = (const float*)d_in[23];
  float* out = (float*)d_out;

  const size_t NEED = (size_t)26576128 * sizeof(float);
  if(ws_size < NEED) return;

  float* ws = (float*)d_ws;
  size_t off = 0;
  float2* CS  = (float2*)(ws + off); off += 32768;
  float* a1   = ws + off; off += 256;
  float* b1   = ws + off; off += 256;
  float* a2   = ws + off; off += 256;
  float* b2   = ws + off; off += 256;
  float* pbeta= ws + off; off += 256;
  float2* Xt2 = (float2*)(ws + off); off += 1081344;
  float* pool = ws + off; off += 17301504;
  float* P    = ws + off; off += 262144;
  float* PAT  = ws + off; off += 32768;
  float2* Xp  = (float2*)(ws + off); off += 262144;
  float* Zslab= ws + off; off += 2097152;
  float2* Bc  = (float2*)(ws + off); off += 262144;
  float* attn = ws + off; off += 4194304;
  float2* Hc  = (float2*)(ws + off); off += 524288;
  float2* Hc2 = (float2*)(ws + off); off += 524288;

  float2* DL  = (float2*)Zslab;        // 2048*132 cplx = 540672 floats
  float* Gp   = attn;                  // 32*2*16384 = 1,048,576 floats
  float* Dout = attn + 1048576;        // 262,144 floats (dead before epi0)

  // pool slots
  float2* Xw = (float2*)pool;          // 256*2112 cplx
  float* R1r = pool + 8650752;
  float* R1i = pool + 8650752 + 1081344;
  float* y0g = pool;                   // after scoresG (Xw dead)
  float* h1  = pool + 4325376;

  k_tables<<<dim3(128), dim3(128), 0, stream>>>(CS);
  k_instats<<<dim3(256), dim3(256), 0, stream>>>(x, norm1_w, norm1_b, a1, b1);
  k_p1<<<dim3(1024), dim3(256), 0, stream>>>(x, R1r, R1i, CS);
  k_p2<<<dim3(256), dim3(704), 0, stream>>>(R1r, R1i, CS, a1, norm1_b, Xt2, Xp);
  k_build_w<<<dim3(256), dim3(256), 0, stream>>>(Xt2, Xw);
  k_build_d<<<dim3(2048), dim3(256), 0, stream>>>(Xt2, kqv_wr, kqv_wi, kqv_bias,
                                                  kqv_sw, kqv_sb, DL);
  k_scoresG<<<dim3(256), dim3(256), 0, stream>>>(Xt2, Xw, Gp);
  k_scoresD<<<dim3(256), dim3(256), 0, stream>>>(Xt2, DL, Dout);
  k_softmax<<<dim3(2048), dim3(64), 0, stream>>>(Gp, Dout, kqv_sw, P);
  k_peff<<<dim3(128), dim3(256), 0, stream>>>(P, p_sw, kqv_sw, a1, PAT);
  k_pbeta<<<dim3(256), dim3(128), 0, stream>>>(P, p_sw, kqv_sw, b1, pbeta);
  k_zcorr<<<dim3(256), dim3(512), 0, stream>>>(P, Xp, kqv_wr, kqv_wi, kqv_bias, kqv_sw, kqv_sb,
                                               p_wr, p_wi, p_bias, p_sw, p_sb, Bc);
  k_attn_gemm<<<dim3(512), dim3(256), 0, stream>>>(PAT, x, pbeta, y0g);
  k_epi0<<<dim3(256), dim3(1024), 0, stream>>>(y0g, x, Bc, CS, attn_norm_w, attn_norm_b,
                                               norm2_w, norm2_b, attn, a2, b2, Hc);
  k_mixinv<<<dim3(256), dim3(1024), 0, stream>>>(Hc, attn, a2, b2, mix_wr, mix_wi,
                                                 mix_sw, mix_sb, CS, 1,
                                                 Hc2, (const float*)nullptr,
                                                 (const float*)nullptr, (const float*)nullptr, h1);
  k_mixinv<<<dim3(256), dim3(1024), 0, stream>>>(Hc2, h1, (const float*)nullptr, (const float*)nullptr,
                                                 mix_wr+8192, mix_wi+8192, mix_sw+16, mix_sb+4, CS, 0,
                                                 (float2*)nullptr, attn, mon_w, mon_b, out);
}